// Round 5
// baseline (1398.049 us; speedup 1.0000x reference)
//
#include <hip/hip_runtime.h>

#define NN 100000
#define NE 1600000
#define F 64

typedef float f32x4 __attribute__((ext_vector_type(4)));

__device__ inline unsigned short f2bf(float f) {          // RTNE float->bf16
    unsigned u = __builtin_bit_cast(unsigned, f);
    u = (u + 0x7fffu + ((u >> 16) & 1u)) >> 16;
    return (unsigned short)u;
}
__device__ inline float bf2f(unsigned short b) { return __builtin_bit_cast(float, (unsigned)b << 16); }
__device__ inline float bflo(unsigned u) { return __builtin_bit_cast(float, u << 16); }
__device__ inline float bfhi(unsigned u) { return __builtin_bit_cast(float, u & 0xffff0000u); }

// ---------------- node transform: f_ni/f_nj/h (all emitted as bf16) ----------------
__global__ __launch_bounds__(256) void node_kernel(
    const float* __restrict__ nfeats,
    const float* __restrict__ W_node, const float* __restrict__ b_node,
    const float* __restrict__ W_ni,   const float* __restrict__ W_nj,
    unsigned short* __restrict__ f_ni16, unsigned short* __restrict__ f_nj16,
    unsigned short* __restrict__ h16)
{
    __shared__ float xs[256 * F];
    const int t = threadIdx.x;
    const int tile0 = blockIdx.x * 256;

    const f32x4* gsrc = reinterpret_cast<const f32x4*>(nfeats + (size_t)tile0 * F);
#pragma unroll
    for (int i = 0; i < 16; ++i) {
        const int idx = i * 256 + t;
        const int row = idx >> 4;
        if (tile0 + row < NN) {
            const f32x4 v = gsrc[idx];
            const int c4 = (idx & 15) << 2;
            float* b = xs + (row << 6);
            b[(c4 + 0 + row) & 63] = v[0];
            b[(c4 + 1 + row) & 63] = v[1];
            b[(c4 + 2 + row) & 63] = v[2];
            b[(c4 + 3 + row) & 63] = v[3];
        }
    }
    __syncthreads();

    const int n = tile0 + t;
    if (n >= NN) return;

    float x[F];
#pragma unroll
    for (int k = 0; k < F; ++k) x[k] = xs[(t << 6) + ((k + t) & 63)];

    ushort4* po = reinterpret_cast<ushort4*>(f_ni16 + (size_t)n * F);
    ushort4* qo = reinterpret_cast<ushort4*>(f_nj16 + (size_t)n * F);
    ushort4* ho = reinterpret_cast<ushort4*>(h16    + (size_t)n * F);

    for (int oc = 0; oc < F; oc += 4) {
        float ai[4], aj[4], ah[4];
#pragma unroll
        for (int j = 0; j < 4; ++j) { ai[j] = 0.f; aj[j] = 0.f; ah[j] = b_node[oc + j]; }
#pragma unroll
        for (int k = 0; k < F; ++k) {
            const float xv = x[k];
#pragma unroll
            for (int j = 0; j < 4; ++j) {
                ai[j] += xv * W_ni  [(oc + j) * F + k];
                aj[j] += xv * W_nj  [(oc + j) * F + k];
                ah[j] += xv * W_node[(oc + j) * F + k];
            }
        }
        ushort4 pi, pj, ph;
        pi.x = f2bf(ai[0]); pi.y = f2bf(ai[1]); pi.z = f2bf(ai[2]); pi.w = f2bf(ai[3]);
        pj.x = f2bf(aj[0]); pj.y = f2bf(aj[1]); pj.z = f2bf(aj[2]); pj.w = f2bf(aj[3]);
        ph.x = f2bf(ah[0]); ph.y = f2bf(ah[1]); ph.z = f2bf(ah[2]); ph.w = f2bf(ah[3]);
        po[oc >> 2] = pi;
        qo[oc >> 2] = pj;
        ho[oc >> 2] = ph;
    }
}

// ---------------- edge update ----------------
// 32 KB LDS (bf16 in-tile, then f32 half-out-tile), bf16 one-line gathers,
// nt streaming loads/stores, 16 waves/CU.
__global__ __launch_bounds__(256, 4) void edge_kernel(
    const float* __restrict__ efeats,
    const int* __restrict__ src, const int* __restrict__ dst,
    const unsigned short* __restrict__ f_ni16, const unsigned short* __restrict__ f_nj16,
    const float* __restrict__ W_fij, const float* __restrict__ bias,
    float* __restrict__ f_out)
{
    __shared__ unsigned short xs16[256 * F];            // 32 KB
    float* xsf = reinterpret_cast<float*>(xs16);        // reused as [256][32] f32
    const int t = threadIdx.x;
    const int tile0 = blockIdx.x * 256;

    const int e = tile0 + t;
    const int s = src[e], d = dst[e];

    // ---- stage-in: linear nt f32x4 loads -> bf16 swizzled LDS (8B granularity)
    const f32x4* gsrc = reinterpret_cast<const f32x4*>(efeats + (size_t)tile0 * F);
#pragma unroll
    for (int i = 0; i < 16; ++i) {
        const int idx = i * 256 + t;
        const f32x4 v = __builtin_nontemporal_load(gsrc + idx);
        const int row = idx >> 4;
        const int g   = idx & 15;
        ushort4 pk;
        pk.x = f2bf(v[0]); pk.y = f2bf(v[1]); pk.z = f2bf(v[2]); pk.w = f2bf(v[3]);
        *reinterpret_cast<ushort4*>(xs16 + (row << 6) + (((g + row) & 15) << 2)) = pk;
    }
    __syncthreads();

    // ---- x readout: 64 fp32 in VGPRs
    float x[F];
#pragma unroll
    for (int g = 0; g < 16; ++g) {
        const ushort4 pk = *reinterpret_cast<const ushort4*>(xs16 + (t << 6) + (((g + t) & 15) << 2));
        x[g * 4 + 0] = bf2f(pk.x);
        x[g * 4 + 1] = bf2f(pk.y);
        x[g * 4 + 2] = bf2f(pk.z);
        x[g * 4 + 3] = bf2f(pk.w);
    }
    __syncthreads();        // input tile dead; xsf now the half-output tile

    const uint4* gi = reinterpret_cast<const uint4*>(f_ni16 + (size_t)s * F);  // row = 8x uint4
    const uint4* gj = reinterpret_cast<const uint4*>(f_nj16 + (size_t)d * F);
    f32x4* gout = reinterpret_cast<f32x4*>(f_out + (size_t)tile0 * F);

#pragma unroll
    for (int half = 0; half < 2; ++half) {
        // gather this half's 64 B of each row (bf16)
        uint4 vni[2], vnj[2];
#pragma unroll
        for (int i = 0; i < 2; ++i) vni[i] = gi[half * 4 + i * 2];
#pragma unroll
        for (int i = 0; i < 2; ++i) vnj[i] = gj[half * 4 + i * 2];
        uint4 vni2[2], vnj2[2];
#pragma unroll
        for (int i = 0; i < 2; ++i) vni2[i] = gi[half * 4 + i * 2 + 1];
#pragma unroll
        for (int i = 0; i < 2; ++i) vnj2[i] = gj[half * 4 + i * 2 + 1];

#pragma unroll
        for (int g = 0; g < 8; ++g) {           // oc = half*32 + g*4
            const int oc = half * 32 + g * 4;
            float a[4];
#pragma unroll
            for (int j = 0; j < 4; ++j) a[j] = bias[oc + j];
#pragma unroll
            for (int k = 0; k < F; ++k) {
                const float xv = x[k];
#pragma unroll
                for (int j = 0; j < 4; ++j) a[j] += xv * W_fij[(oc + j) * F + k];
            }
            // unpack gather bf16: uint4 q covers 8 cols; g selects 4
            const uint4 wi = (g & 2) ? ((g & 4) ? vni2[1] : vni2[0]) : ((g & 4) ? vni[1] : vni[0]);
            const uint4 wj = (g & 2) ? ((g & 4) ? vnj2[1] : vnj2[0]) : ((g & 4) ? vnj[1] : vnj[0]);
            const unsigned i01 = (g & 1) ? wi.z : wi.x;
            const unsigned i23 = (g & 1) ? wi.w : wi.y;
            const unsigned j01 = (g & 1) ? wj.z : wj.x;
            const unsigned j23 = (g & 1) ? wj.w : wj.y;
            float v0 = a[0] + bflo(i01) + bflo(j01);
            float v1 = a[1] + bfhi(i01) + bfhi(j01);
            float v2 = a[2] + bflo(i23) + bflo(j23);
            float v3 = a[3] + bfhi(i23) + bfhi(j23);
            v0 = (v0 > 0.f) ? v0 : 0.01f * v0;
            v1 = (v1 > 0.f) ? v1 : 0.01f * v1;
            v2 = (v2 > 0.f) ? v2 : 0.01f * v2;
            v3 = (v3 > 0.f) ? v3 : 0.01f * v3;
            const int cl = g * 4;               // local col 0..31
            float* ob = xsf + (t << 5);
            ob[(cl + 0 + t) & 31] = v0;
            ob[(cl + 1 + t) & 31] = v1;
            ob[(cl + 2 + t) & 31] = v2;
            ob[(cl + 3 + t) & 31] = v3;
        }
        __syncthreads();

        // ---- stage-out this half: swizzled LDS reads, linear nt f32x4 stores (full lines)
#pragma unroll
        for (int i = 0; i < 8; ++i) {
            const int idx = i * 256 + t;        // 0..2047
            const int row = idx >> 3;           // 0..255
            const int c4  = (idx & 7) << 2;     // 0..28
            const float* b = xsf + (row << 5);
            f32x4 v;
            v[0] = b[(c4 + 0 + row) & 31];
            v[1] = b[(c4 + 1 + row) & 31];
            v[2] = b[(c4 + 2 + row) & 31];
            v[3] = b[(c4 + 3 + row) & 31];
            __builtin_nontemporal_store(v, gout + row * 16 + half * 8 + (idx & 7));
        }
        __syncthreads();
    }
}

// ---------------- CSR build step 1: in-degree histogram ----------------
__global__ __launch_bounds__(256) void hist_kernel(
    const int* __restrict__ dst, int* __restrict__ counts)
{
    const int e = blockIdx.x * 256 + threadIdx.x;
    if (e >= NE) return;
    atomicAdd(&counts[dst[e]], 1);
}

// ---------------- CSR build step 2: exclusive scan (single block, two-pass) ----------------
__global__ __launch_bounds__(1024) void scan_kernel(
    const int* __restrict__ counts, int* __restrict__ offsets, int* __restrict__ cursor)
{
    __shared__ int sdata[1024];
    const int t = threadIdx.x;
    const int CH = (NN + 1023) / 1024;   // 98
    const int base = t * CH;

    int mysum = 0;
    for (int i = 0; i < CH; ++i) {
        const int idx = base + i;
        if (idx < NN) mysum += counts[idx];
    }
    sdata[t] = mysum;
    __syncthreads();
    for (int off = 1; off < 1024; off <<= 1) {
        int v = (t >= off) ? sdata[t - off] : 0;
        __syncthreads();
        sdata[t] += v;
        __syncthreads();
    }
    int running = sdata[t] - mysum;      // exclusive prefix
    for (int i = 0; i < CH; ++i) {
        const int idx = base + i;
        if (idx < NN) {
            offsets[idx] = running;
            cursor[idx]  = running;
            running += counts[idx];
        }
    }
    if (t == 1023) offsets[NN] = running;   // == NE
}

// ---------------- CSR build step 3: placement ----------------
__global__ __launch_bounds__(256) void place_kernel(
    const int* __restrict__ src, const int* __restrict__ dst,
    int* __restrict__ cursor, int* __restrict__ eidx)
{
    const int e = blockIdx.x * 256 + threadIdx.x;
    if (e >= NE) return;
    const int pos = atomicAdd(&cursor[dst[e]], 1);
    eidx[pos] = src[e];
}

// ---------------- aggregation: wave per node, lane = column, bf16 h ----------------
__global__ __launch_bounds__(256) void gather_kernel(
    const unsigned short* __restrict__ h16, const int* __restrict__ offsets,
    const int* __restrict__ eidx, float* __restrict__ h_out)
{
    const int n = blockIdx.x * 4 + (threadIdx.x >> 6);
    const int lane = threadIdx.x & 63;
    if (n >= NN) return;
    const int beg = offsets[n], end = offsets[n + 1];
    float acc = 0.f;
    int k = beg;
    for (; k + 4 <= end; k += 4) {
        const int s0 = eidx[k], s1 = eidx[k + 1], s2 = eidx[k + 2], s3 = eidx[k + 3];
        const float v0 = bf2f(h16[(size_t)s0 * F + lane]);
        const float v1 = bf2f(h16[(size_t)s1 * F + lane]);
        const float v2 = bf2f(h16[(size_t)s2 * F + lane]);
        const float v3 = bf2f(h16[(size_t)s3 * F + lane]);
        acc += v0; acc += v1; acc += v2; acc += v3;
    }
    for (; k < end; ++k) acc += bf2f(h16[(size_t)eidx[k] * F + lane]);
    const float deg = (float)(end - beg);
    __builtin_nontemporal_store(acc / fmaxf(deg, 1.0f), h_out + (size_t)n * F + lane);
}

extern "C" void kernel_launch(void* const* d_in, const int* in_sizes, int n_in,
                              void* d_out, int out_size, void* d_ws, size_t ws_size,
                              hipStream_t stream)
{
    const float* nfeats = (const float*)d_in[0];
    const float* efeats = (const float*)d_in[1];
    const int*   src    = (const int*)  d_in[2];
    const int*   dst    = (const int*)  d_in[3];
    const float* W_node = (const float*)d_in[4];
    const float* b_node = (const float*)d_in[5];
    const float* W_ni   = (const float*)d_in[6];
    const float* W_nj   = (const float*)d_in[7];
    const float* W_fij  = (const float*)d_in[8];
    const float* bias   = (const float*)d_in[9];

    float* h_out = (float*)d_out;                   // [NN, F]
    float* f_out = (float*)d_out + (size_t)NN * F;  // [NE, F]

    unsigned short* f_ni16 = (unsigned short*)d_ws;            // bf16 tables
    unsigned short* f_nj16 = f_ni16 + (size_t)NN * F;
    unsigned short* h16    = f_nj16 + (size_t)NN * F;
    int*   offsets = (int*)(h16 + (size_t)NN * F);  // NN+1
    int*   cursor  = offsets + (NN + 1);            // NN
    int*   counts  = cursor + NN;                   // NN
    int*   eidx    = counts + NN;                   // NE
    const size_t need = ((size_t)3 * NN * F) * sizeof(unsigned short)
                      + ((size_t)(3 * NN + 1) + NE) * sizeof(int);
    if (ws_size < need) return;

    hipMemsetAsync(counts, 0, (size_t)NN * sizeof(int), stream);

    node_kernel<<<(NN + 255) / 256, 256, 0, stream>>>(nfeats, W_node, b_node, W_ni, W_nj, f_ni16, f_nj16, h16);
    edge_kernel<<<NE / 256, 256, 0, stream>>>(efeats, src, dst, f_ni16, f_nj16, W_fij, bias, f_out);
    hist_kernel<<<(NE + 255) / 256, 256, 0, stream>>>(dst, counts);
    scan_kernel<<<1, 1024, 0, stream>>>(counts, offsets, cursor);
    place_kernel<<<(NE + 255) / 256, 256, 0, stream>>>(src, dst, cursor, eidx);
    gather_kernel<<<(NN + 3) / 4, 256, 0, stream>>>(h16, offsets, eidx, h_out);
}

// Round 6
// 1147.367 us; speedup vs baseline: 1.2185x; 1.2185x over previous
//
#include <hip/hip_runtime.h>

#define NN 100000
#define NE 1600000
#define F 64

typedef float f32x4 __attribute__((ext_vector_type(4)));

__device__ inline unsigned short f2bf(float f) {          // RTNE float->bf16
    unsigned u = __builtin_bit_cast(unsigned, f);
    u = (u + 0x7fffu + ((u >> 16) & 1u)) >> 16;
    return (unsigned short)u;
}
__device__ inline float bf2f(unsigned short b) { return __builtin_bit_cast(float, (unsigned)b << 16); }
__device__ inline float bflo(unsigned u) { return __builtin_bit_cast(float, u << 16); }
__device__ inline float bfhi(unsigned u) { return __builtin_bit_cast(float, u & 0xffff0000u); }

// ---------------- node transform: f_ni/f_nj/h (all emitted as bf16) ----------------
__global__ __launch_bounds__(256) void node_kernel(
    const float* __restrict__ nfeats,
    const float* __restrict__ W_node, const float* __restrict__ b_node,
    const float* __restrict__ W_ni,   const float* __restrict__ W_nj,
    unsigned short* __restrict__ f_ni16, unsigned short* __restrict__ f_nj16,
    unsigned short* __restrict__ h16)
{
    __shared__ float xs[256 * F];
    const int t = threadIdx.x;
    const int tile0 = blockIdx.x * 256;

    const f32x4* gsrc = reinterpret_cast<const f32x4*>(nfeats + (size_t)tile0 * F);
#pragma unroll
    for (int i = 0; i < 16; ++i) {
        const int idx = i * 256 + t;
        const int row = idx >> 4;
        if (tile0 + row < NN) {
            const f32x4 v = gsrc[idx];
            const int c4 = (idx & 15) << 2;
            float* b = xs + (row << 6);
            b[(c4 + 0 + row) & 63] = v[0];
            b[(c4 + 1 + row) & 63] = v[1];
            b[(c4 + 2 + row) & 63] = v[2];
            b[(c4 + 3 + row) & 63] = v[3];
        }
    }
    __syncthreads();

    const int n = tile0 + t;
    if (n >= NN) return;

    float x[F];
#pragma unroll
    for (int k = 0; k < F; ++k) x[k] = xs[(t << 6) + ((k + t) & 63)];

    ushort4* po = reinterpret_cast<ushort4*>(f_ni16 + (size_t)n * F);
    ushort4* qo = reinterpret_cast<ushort4*>(f_nj16 + (size_t)n * F);
    ushort4* ho = reinterpret_cast<ushort4*>(h16    + (size_t)n * F);

    for (int oc = 0; oc < F; oc += 4) {
        float ai[4], aj[4], ah[4];
#pragma unroll
        for (int j = 0; j < 4; ++j) { ai[j] = 0.f; aj[j] = 0.f; ah[j] = b_node[oc + j]; }
#pragma unroll
        for (int k = 0; k < F; ++k) {
            const float xv = x[k];
#pragma unroll
            for (int j = 0; j < 4; ++j) {
                ai[j] += xv * W_ni  [(oc + j) * F + k];
                aj[j] += xv * W_nj  [(oc + j) * F + k];
                ah[j] += xv * W_node[(oc + j) * F + k];
            }
        }
        ushort4 pi, pj, ph;
        pi.x = f2bf(ai[0]); pi.y = f2bf(ai[1]); pi.z = f2bf(ai[2]); pi.w = f2bf(ai[3]);
        pj.x = f2bf(aj[0]); pj.y = f2bf(aj[1]); pj.z = f2bf(aj[2]); pj.w = f2bf(aj[3]);
        ph.x = f2bf(ah[0]); ph.y = f2bf(ah[1]); ph.z = f2bf(ah[2]); ph.w = f2bf(ah[3]);
        po[oc >> 2] = pi;
        qo[oc >> 2] = pj;
        ho[oc >> 2] = ph;
    }
}

// ---------------- edge update ----------------
// 32 KB LDS (bf16 in-tile, then f32 half-out-tile), bf16 one-line gathers,
// nt streaming loads/stores. launch_bounds(256,2): VGPR cap 256 -> no spills
// (round-5's (256,4) cap=128 forced x[64] to scratch: WRITE 0.5->1.36 GB).
__global__ __launch_bounds__(256, 2) void edge_kernel(
    const float* __restrict__ efeats,
    const int* __restrict__ src, const int* __restrict__ dst,
    const unsigned short* __restrict__ f_ni16, const unsigned short* __restrict__ f_nj16,
    const float* __restrict__ W_fij, const float* __restrict__ bias,
    float* __restrict__ f_out)
{
    __shared__ unsigned short xs16[256 * F];            // 32 KB
    float* xsf = reinterpret_cast<float*>(xs16);        // reused as [256][32] f32
    const int t = threadIdx.x;
    const int tile0 = blockIdx.x * 256;

    const int e = tile0 + t;
    const int s = src[e], d = dst[e];

    // ---- stage-in: linear nt f32x4 loads -> bf16 swizzled LDS (8B granularity)
    const f32x4* gsrc = reinterpret_cast<const f32x4*>(efeats + (size_t)tile0 * F);
#pragma unroll
    for (int i = 0; i < 16; ++i) {
        const int idx = i * 256 + t;
        const f32x4 v = __builtin_nontemporal_load(gsrc + idx);
        const int row = idx >> 4;
        const int g   = idx & 15;
        ushort4 pk;
        pk.x = f2bf(v[0]); pk.y = f2bf(v[1]); pk.z = f2bf(v[2]); pk.w = f2bf(v[3]);
        *reinterpret_cast<ushort4*>(xs16 + (row << 6) + (((g + row) & 15) << 2)) = pk;
    }
    __syncthreads();

    // ---- x readout: 64 fp32 in VGPRs
    float x[F];
#pragma unroll
    for (int g = 0; g < 16; ++g) {
        const ushort4 pk = *reinterpret_cast<const ushort4*>(xs16 + (t << 6) + (((g + t) & 15) << 2));
        x[g * 4 + 0] = bf2f(pk.x);
        x[g * 4 + 1] = bf2f(pk.y);
        x[g * 4 + 2] = bf2f(pk.z);
        x[g * 4 + 3] = bf2f(pk.w);
    }
    __syncthreads();        // input tile dead; xsf now the half-output tile

    const uint4* gi = reinterpret_cast<const uint4*>(f_ni16 + (size_t)s * F);  // row = 8x uint4
    const uint4* gj = reinterpret_cast<const uint4*>(f_nj16 + (size_t)d * F);
    f32x4* gout = reinterpret_cast<f32x4*>(f_out + (size_t)tile0 * F);

#pragma unroll
    for (int half = 0; half < 2; ++half) {
        // gather this half's 64 B of each row (bf16)
        uint4 vni[2], vnj[2];
#pragma unroll
        for (int i = 0; i < 2; ++i) vni[i] = gi[half * 4 + i * 2];
#pragma unroll
        for (int i = 0; i < 2; ++i) vnj[i] = gj[half * 4 + i * 2];
        uint4 vni2[2], vnj2[2];
#pragma unroll
        for (int i = 0; i < 2; ++i) vni2[i] = gi[half * 4 + i * 2 + 1];
#pragma unroll
        for (int i = 0; i < 2; ++i) vnj2[i] = gj[half * 4 + i * 2 + 1];

#pragma unroll
        for (int g = 0; g < 8; ++g) {           // oc = half*32 + g*4
            const int oc = half * 32 + g * 4;
            float a[4];
#pragma unroll
            for (int j = 0; j < 4; ++j) a[j] = bias[oc + j];
#pragma unroll
            for (int k = 0; k < F; ++k) {
                const float xv = x[k];
#pragma unroll
                for (int j = 0; j < 4; ++j) a[j] += xv * W_fij[(oc + j) * F + k];
            }
            // unpack gather bf16: uint4 q covers 8 cols; g selects 4
            const uint4 wi = (g & 2) ? ((g & 4) ? vni2[1] : vni2[0]) : ((g & 4) ? vni[1] : vni[0]);
            const uint4 wj = (g & 2) ? ((g & 4) ? vnj2[1] : vnj2[0]) : ((g & 4) ? vnj[1] : vnj[0]);
            const unsigned i01 = (g & 1) ? wi.z : wi.x;
            const unsigned i23 = (g & 1) ? wi.w : wi.y;
            const unsigned j01 = (g & 1) ? wj.z : wj.x;
            const unsigned j23 = (g & 1) ? wj.w : wj.y;
            float v0 = a[0] + bflo(i01) + bflo(j01);
            float v1 = a[1] + bfhi(i01) + bfhi(j01);
            float v2 = a[2] + bflo(i23) + bflo(j23);
            float v3 = a[3] + bfhi(i23) + bfhi(j23);
            v0 = (v0 > 0.f) ? v0 : 0.01f * v0;
            v1 = (v1 > 0.f) ? v1 : 0.01f * v1;
            v2 = (v2 > 0.f) ? v2 : 0.01f * v2;
            v3 = (v3 > 0.f) ? v3 : 0.01f * v3;
            const int cl = g * 4;               // local col 0..31
            float* ob = xsf + (t << 5);
            ob[(cl + 0 + t) & 31] = v0;
            ob[(cl + 1 + t) & 31] = v1;
            ob[(cl + 2 + t) & 31] = v2;
            ob[(cl + 3 + t) & 31] = v3;
        }
        __syncthreads();

        // ---- stage-out this half: swizzled LDS reads, linear nt f32x4 stores (full lines)
#pragma unroll
        for (int i = 0; i < 8; ++i) {
            const int idx = i * 256 + t;        // 0..2047
            const int row = idx >> 3;           // 0..255
            const int c4  = (idx & 7) << 2;     // 0..28
            const float* b = xsf + (row << 5);
            f32x4 v;
            v[0] = b[(c4 + 0 + row) & 31];
            v[1] = b[(c4 + 1 + row) & 31];
            v[2] = b[(c4 + 2 + row) & 31];
            v[3] = b[(c4 + 3 + row) & 31];
            __builtin_nontemporal_store(v, gout + row * 16 + half * 8 + (idx & 7));
        }
        __syncthreads();
    }
}

// ---------------- CSR build step 1: in-degree histogram ----------------
__global__ __launch_bounds__(256) void hist_kernel(
    const int* __restrict__ dst, int* __restrict__ counts)
{
    const int e = blockIdx.x * 256 + threadIdx.x;
    if (e >= NE) return;
    atomicAdd(&counts[dst[e]], 1);
}

// ---------------- CSR build step 2: exclusive scan (single block, two-pass) ----------------
__global__ __launch_bounds__(1024) void scan_kernel(
    const int* __restrict__ counts, int* __restrict__ offsets, int* __restrict__ cursor)
{
    __shared__ int sdata[1024];
    const int t = threadIdx.x;
    const int CH = (NN + 1023) / 1024;   // 98
    const int base = t * CH;

    int mysum = 0;
    for (int i = 0; i < CH; ++i) {
        const int idx = base + i;
        if (idx < NN) mysum += counts[idx];
    }
    sdata[t] = mysum;
    __syncthreads();
    for (int off = 1; off < 1024; off <<= 1) {
        int v = (t >= off) ? sdata[t - off] : 0;
        __syncthreads();
        sdata[t] += v;
        __syncthreads();
    }
    int running = sdata[t] - mysum;      // exclusive prefix
    for (int i = 0; i < CH; ++i) {
        const int idx = base + i;
        if (idx < NN) {
            offsets[idx] = running;
            cursor[idx]  = running;
            running += counts[idx];
        }
    }
    if (t == 1023) offsets[NN] = running;   // == NE
}

// ---------------- CSR build step 3: placement ----------------
__global__ __launch_bounds__(256) void place_kernel(
    const int* __restrict__ src, const int* __restrict__ dst,
    int* __restrict__ cursor, int* __restrict__ eidx)
{
    const int e = blockIdx.x * 256 + threadIdx.x;
    if (e >= NE) return;
    const int pos = atomicAdd(&cursor[dst[e]], 1);
    eidx[pos] = src[e];
}

// ---------------- aggregation: wave per node, lane = column, bf16 h ----------------
__global__ __launch_bounds__(256) void gather_kernel(
    const unsigned short* __restrict__ h16, const int* __restrict__ offsets,
    const int* __restrict__ eidx, float* __restrict__ h_out)
{
    const int n = blockIdx.x * 4 + (threadIdx.x >> 6);
    const int lane = threadIdx.x & 63;
    if (n >= NN) return;
    const int beg = offsets[n], end = offsets[n + 1];
    float acc = 0.f;
    int k = beg;
    for (; k + 4 <= end; k += 4) {
        const int s0 = eidx[k], s1 = eidx[k + 1], s2 = eidx[k + 2], s3 = eidx[k + 3];
        const float v0 = bf2f(h16[(size_t)s0 * F + lane]);
        const float v1 = bf2f(h16[(size_t)s1 * F + lane]);
        const float v2 = bf2f(h16[(size_t)s2 * F + lane]);
        const float v3 = bf2f(h16[(size_t)s3 * F + lane]);
        acc += v0; acc += v1; acc += v2; acc += v3;
    }
    for (; k < end; ++k) acc += bf2f(h16[(size_t)eidx[k] * F + lane]);
    const float deg = (float)(end - beg);
    __builtin_nontemporal_store(acc / fmaxf(deg, 1.0f), h_out + (size_t)n * F + lane);
}

extern "C" void kernel_launch(void* const* d_in, const int* in_sizes, int n_in,
                              void* d_out, int out_size, void* d_ws, size_t ws_size,
                              hipStream_t stream)
{
    const float* nfeats = (const float*)d_in[0];
    const float* efeats = (const float*)d_in[1];
    const int*   src    = (const int*)  d_in[2];
    const int*   dst    = (const int*)  d_in[3];
    const float* W_node = (const float*)d_in[4];
    const float* b_node = (const float*)d_in[5];
    const float* W_ni   = (const float*)d_in[6];
    const float* W_nj   = (const float*)d_in[7];
    const float* W_fij  = (const float*)d_in[8];
    const float* bias   = (const float*)d_in[9];

    float* h_out = (float*)d_out;                   // [NN, F]
    float* f_out = (float*)d_out + (size_t)NN * F;  // [NE, F]

    unsigned short* f_ni16 = (unsigned short*)d_ws;            // bf16 tables
    unsigned short* f_nj16 = f_ni16 + (size_t)NN * F;
    unsigned short* h16    = f_nj16 + (size_t)NN * F;
    int*   offsets = (int*)(h16 + (size_t)NN * F);  // NN+1
    int*   cursor  = offsets + (NN + 1);            // NN
    int*   counts  = cursor + NN;                   // NN
    int*   eidx    = counts + NN;                   // NE
    const size_t need = ((size_t)3 * NN * F) * sizeof(unsigned short)
                      + ((size_t)(3 * NN + 1) + NE) * sizeof(int);
    if (ws_size < need) return;

    hipMemsetAsync(counts, 0, (size_t)NN * sizeof(int), stream);

    node_kernel<<<(NN + 255) / 256, 256, 0, stream>>>(nfeats, W_node, b_node, W_ni, W_nj, f_ni16, f_nj16, h16);
    edge_kernel<<<NE / 256, 256, 0, stream>>>(efeats, src, dst, f_ni16, f_nj16, W_fij, bias, f_out);
    hist_kernel<<<(NE + 255) / 256, 256, 0, stream>>>(dst, counts);
    scan_kernel<<<1, 1024, 0, stream>>>(counts, offsets, cursor);
    place_kernel<<<(NE + 255) / 256, 256, 0, stream>>>(src, dst, cursor, eidx);
    gather_kernel<<<(NN + 3) / 4, 256, 0, stream>>>(h16, offsets, eidx, h_out);
}

// Round 7
// 872.762 us; speedup vs baseline: 1.6019x; 1.3146x over previous
//
#include <hip/hip_runtime.h>

#define NN 100000
#define NE 1600000
#define F 64

typedef float f32x4 __attribute__((ext_vector_type(4)));
typedef short bf16x8 __attribute__((ext_vector_type(8)));

__device__ inline unsigned short f2bf(float f) {          // RTNE float->bf16
    unsigned u = __builtin_bit_cast(unsigned, f);
    u = (u + 0x7fffu + ((u >> 16) & 1u)) >> 16;
    return (unsigned short)u;
}
__device__ inline float bf2f(unsigned short b) { return __builtin_bit_cast(float, (unsigned)b << 16); }
__device__ inline float bflo(unsigned u) { return __builtin_bit_cast(float, u << 16); }
__device__ inline float bfhi(unsigned u) { return __builtin_bit_cast(float, u & 0xffff0000u); }

// ---------------- node transform: f_ni/f_nj/h (all emitted as bf16) ----------------
__global__ __launch_bounds__(256) void node_kernel(
    const float* __restrict__ nfeats,
    const float* __restrict__ W_node, const float* __restrict__ b_node,
    const float* __restrict__ W_ni,   const float* __restrict__ W_nj,
    unsigned short* __restrict__ f_ni16, unsigned short* __restrict__ f_nj16,
    unsigned short* __restrict__ h16)
{
    __shared__ float xs[256 * F];
    const int t = threadIdx.x;
    const int tile0 = blockIdx.x * 256;

    const f32x4* gsrc = reinterpret_cast<const f32x4*>(nfeats + (size_t)tile0 * F);
#pragma unroll
    for (int i = 0; i < 16; ++i) {
        const int idx = i * 256 + t;
        const int row = idx >> 4;
        if (tile0 + row < NN) {
            const f32x4 v = gsrc[idx];
            const int c4 = (idx & 15) << 2;
            float* b = xs + (row << 6);
            b[(c4 + 0 + row) & 63] = v[0];
            b[(c4 + 1 + row) & 63] = v[1];
            b[(c4 + 2 + row) & 63] = v[2];
            b[(c4 + 3 + row) & 63] = v[3];
        }
    }
    __syncthreads();

    const int n = tile0 + t;
    if (n >= NN) return;

    float x[F];
#pragma unroll
    for (int k = 0; k < F; ++k) x[k] = xs[(t << 6) + ((k + t) & 63)];

    ushort4* po = reinterpret_cast<ushort4*>(f_ni16 + (size_t)n * F);
    ushort4* qo = reinterpret_cast<ushort4*>(f_nj16 + (size_t)n * F);
    ushort4* ho = reinterpret_cast<ushort4*>(h16    + (size_t)n * F);

    for (int oc = 0; oc < F; oc += 4) {
        float ai[4], aj[4], ah[4];
#pragma unroll
        for (int j = 0; j < 4; ++j) { ai[j] = 0.f; aj[j] = 0.f; ah[j] = b_node[oc + j]; }
#pragma unroll
        for (int k = 0; k < F; ++k) {
            const float xv = x[k];
#pragma unroll
            for (int j = 0; j < 4; ++j) {
                ai[j] += xv * W_ni  [(oc + j) * F + k];
                aj[j] += xv * W_nj  [(oc + j) * F + k];
                ah[j] += xv * W_node[(oc + j) * F + k];
            }
        }
        ushort4 pi, pj, ph;
        pi.x = f2bf(ai[0]); pi.y = f2bf(ai[1]); pi.z = f2bf(ai[2]); pi.w = f2bf(ai[3]);
        pj.x = f2bf(aj[0]); pj.y = f2bf(aj[1]); pj.z = f2bf(aj[2]); pj.w = f2bf(aj[3]);
        ph.x = f2bf(ah[0]); ph.y = f2bf(ah[1]); ph.z = f2bf(ah[2]); ph.w = f2bf(ah[3]);
        po[oc >> 2] = pi;
        qo[oc >> 2] = pj;
        ho[oc >> 2] = ph;
    }
}

// ---------------- edge update via bf16 MFMA ----------------
// Per 256-edge block: A = efeats tile (bf16, LDS, 16B chunks slot^=(row&7)),
// B = W_fij (bf16 LDS, [col][k] = B^T form). 4 waves x (64 edges x 64 cols),
// mfma_f32_16x16x32_bf16. Epilogue reuses A-LDS as f32 D-half-tile (32 cols),
// per-thread gather/bias/leaky finish, linear nt stage-out.
__global__ __launch_bounds__(256) void edge_kernel(
    const float* __restrict__ efeats,
    const int* __restrict__ src, const int* __restrict__ dst,
    const unsigned short* __restrict__ f_ni16, const unsigned short* __restrict__ f_nj16,
    const float* __restrict__ W_fij, const float* __restrict__ bias,
    float* __restrict__ f_out)
{
    __shared__ bf16x8 As8[256 * 8];   // 32 KB: A tile / later D half-tile (f32 [256][32])
    __shared__ bf16x8 Ws8[64 * 8];    //  8 KB: W tile
    float* Df = reinterpret_cast<float*>(As8);

    const int t = threadIdx.x;
    const int w = t >> 6, lane = t & 63;
    const int tile0 = blockIdx.x * 256;
    const int e = tile0 + t;
    const int s = src[e], d = dst[e];

    // ---- stage W: 64x64 f32 -> bf16 chunks (2 chunks/thread)
    {
        const f32x4* gw = reinterpret_cast<const f32x4*>(W_fij);
#pragma unroll
        for (int i = 0; i < 2; ++i) {
            const int c = i * 256 + t;              // chunk 0..511
            const int row = c >> 3, slot = c & 7;
            const f32x4 v0 = gw[2 * c], v1 = gw[2 * c + 1];
            bf16x8 pk;
            pk[0] = (short)f2bf(v0[0]); pk[1] = (short)f2bf(v0[1]);
            pk[2] = (short)f2bf(v0[2]); pk[3] = (short)f2bf(v0[3]);
            pk[4] = (short)f2bf(v1[0]); pk[5] = (short)f2bf(v1[1]);
            pk[6] = (short)f2bf(v1[2]); pk[7] = (short)f2bf(v1[3]);
            Ws8[row * 8 + (slot ^ (row & 7))] = pk;
        }
    }
    // ---- stage A: efeats tile, linear nt loads, bf16 pack, swizzled chunks
    {
        const f32x4* gsrc = reinterpret_cast<const f32x4*>(efeats + (size_t)tile0 * F);
#pragma unroll
        for (int i = 0; i < 8; ++i) {
            const int c = i * 256 + t;              // chunk 0..2047
            const int row = c >> 3, slot = c & 7;
            const f32x4 v0 = __builtin_nontemporal_load(gsrc + 2 * c);
            const f32x4 v1 = __builtin_nontemporal_load(gsrc + 2 * c + 1);
            bf16x8 pk;
            pk[0] = (short)f2bf(v0[0]); pk[1] = (short)f2bf(v0[1]);
            pk[2] = (short)f2bf(v0[2]); pk[3] = (short)f2bf(v0[3]);
            pk[4] = (short)f2bf(v1[0]); pk[5] = (short)f2bf(v1[1]);
            pk[6] = (short)f2bf(v1[2]); pk[7] = (short)f2bf(v1[3]);
            As8[row * 8 + (slot ^ (row & 7))] = pk;
        }
    }
    // gather loads, half 0 (cols 0..31): 64B per table row
    const uint4* gi = reinterpret_cast<const uint4*>(f_ni16 + (size_t)s * F);
    const uint4* gj = reinterpret_cast<const uint4*>(f_nj16 + (size_t)d * F);
    uint4 vni[4], vnj[4];
#pragma unroll
    for (int i = 0; i < 4; ++i) { vni[i] = gi[i]; vnj[i] = gj[i]; }

    __syncthreads();

    // ---- fragment loads (ds_read_b128, conflict-free via slot swizzle)
    bf16x8 af[4][2], bfr[4][2];
#pragma unroll
    for (int mt = 0; mt < 4; ++mt)
#pragma unroll
        for (int ks = 0; ks < 2; ++ks) {
            const int row = w * 64 + mt * 16 + (lane & 15);
            const int kslot = ks * 4 + (lane >> 4);
            af[mt][ks] = As8[row * 8 + (kslot ^ (row & 7))];
        }
#pragma unroll
    for (int nt = 0; nt < 4; ++nt)
#pragma unroll
        for (int ks = 0; ks < 2; ++ks) {
            const int c = nt * 16 + (lane & 15);
            const int kslot = ks * 4 + (lane >> 4);
            bfr[nt][ks] = Ws8[c * 8 + (kslot ^ (c & 7))];
        }

    f32x4 acc[4][4];
#pragma unroll
    for (int mt = 0; mt < 4; ++mt)
#pragma unroll
        for (int nt = 0; nt < 4; ++nt) acc[mt][nt] = f32x4{0.f, 0.f, 0.f, 0.f};

#pragma unroll
    for (int ks = 0; ks < 2; ++ks)
#pragma unroll
        for (int mt = 0; mt < 4; ++mt)
#pragma unroll
            for (int nt = 0; nt < 4; ++nt)
                acc[mt][nt] = __builtin_amdgcn_mfma_f32_16x16x32_bf16(
                    af[mt][ks], bfr[nt][ks], acc[mt][nt], 0, 0, 0);

    __syncthreads();        // all A/W ds_reads done; As8 reusable as Df

    f32x4* gout = reinterpret_cast<f32x4*>(f_out + (size_t)tile0 * F);

#pragma unroll
    for (int half = 0; half < 2; ++half) {
        // ---- scatter acc (this half's 2 n-tiles) into swizzled f32 D-tile
#pragma unroll
        for (int mt = 0; mt < 4; ++mt)
#pragma unroll
            for (int ntl = 0; ntl < 2; ++ntl) {
                const int nt = half * 2 + ntl;
#pragma unroll
                for (int r = 0; r < 4; ++r) {
                    const int row = w * 64 + mt * 16 + (lane >> 4) * 4 + r;
                    const int col = ntl * 16 + (lane & 15);
                    Df[row * 32 + ((col + row) & 31)] = acc[mt][nt][r];
                }
            }
        // prefetch next half's gathers (latency hides under epilogue)
        uint4 nni[4], nnj[4];
        if (half == 0) {
#pragma unroll
            for (int i = 0; i < 4; ++i) { nni[i] = gi[4 + i]; nnj[i] = gj[4 + i]; }
        }
        __syncthreads();

        // ---- per-thread row finish: +gathers +bias, leaky, write back in place
        float* rb = Df + t * 32;
#pragma unroll
        for (int c = 0; c < 32; ++c) {
            float v = rb[(c + t) & 31];
            const unsigned wi = vni[c >> 3][(c >> 1) & 3];
            const unsigned wj = vnj[c >> 3][(c >> 1) & 3];
            v += (c & 1) ? bfhi(wi) : bflo(wi);
            v += (c & 1) ? bfhi(wj) : bflo(wj);
            v += bias[half * 32 + c];
            v = (v > 0.f) ? v : 0.01f * v;
            rb[(c + t) & 31] = v;
        }
        __syncthreads();

        // ---- stage-out: swizzled LDS reads, linear nt f32x4 stores
#pragma unroll
        for (int i = 0; i < 8; ++i) {
            const int idx = i * 256 + t;
            const int row = idx >> 3;
            const int c4 = (idx & 7) << 2;
            const float* b = Df + row * 32;
            f32x4 v;
            v[0] = b[(c4 + 0 + row) & 31];
            v[1] = b[(c4 + 1 + row) & 31];
            v[2] = b[(c4 + 2 + row) & 31];
            v[3] = b[(c4 + 3 + row) & 31];
            __builtin_nontemporal_store(v, gout + row * 16 + half * 8 + (idx & 7));
        }
        if (half == 0) {
            __syncthreads();    // protect Df before half1 overwrites
#pragma unroll
            for (int i = 0; i < 4; ++i) { vni[i] = nni[i]; vnj[i] = nnj[i]; }
        }
    }
}

// ---------------- CSR build step 1: in-degree histogram ----------------
__global__ __launch_bounds__(256) void hist_kernel(
    const int* __restrict__ dst, int* __restrict__ counts)
{
    const int e = blockIdx.x * 256 + threadIdx.x;
    if (e >= NE) return;
    atomicAdd(&counts[dst[e]], 1);
}

// ---------------- CSR build step 2: exclusive scan (single block, two-pass) ----------------
__global__ __launch_bounds__(1024) void scan_kernel(
    const int* __restrict__ counts, int* __restrict__ offsets, int* __restrict__ cursor)
{
    __shared__ int sdata[1024];
    const int t = threadIdx.x;
    const int CH = (NN + 1023) / 1024;   // 98
    const int base = t * CH;

    int mysum = 0;
    for (int i = 0; i < CH; ++i) {
        const int idx = base + i;
        if (idx < NN) mysum += counts[idx];
    }
    sdata[t] = mysum;
    __syncthreads();
    for (int off = 1; off < 1024; off <<= 1) {
        int v = (t >= off) ? sdata[t - off] : 0;
        __syncthreads();
        sdata[t] += v;
        __syncthreads();
    }
    int running = sdata[t] - mysum;      // exclusive prefix
    for (int i = 0; i < CH; ++i) {
        const int idx = base + i;
        if (idx < NN) {
            offsets[idx] = running;
            cursor[idx]  = running;
            running += counts[idx];
        }
    }
    if (t == 1023) offsets[NN] = running;   // == NE
}

// ---------------- CSR build step 3: placement ----------------
__global__ __launch_bounds__(256) void place_kernel(
    const int* __restrict__ src, const int* __restrict__ dst,
    int* __restrict__ cursor, int* __restrict__ eidx)
{
    const int e = blockIdx.x * 256 + threadIdx.x;
    if (e >= NE) return;
    const int pos = atomicAdd(&cursor[dst[e]], 1);
    eidx[pos] = src[e];
}

// ---------------- aggregation: wave per node, lane = column, bf16 h ----------------
__global__ __launch_bounds__(256) void gather_kernel(
    const unsigned short* __restrict__ h16, const int* __restrict__ offsets,
    const int* __restrict__ eidx, float* __restrict__ h_out)
{
    const int n = blockIdx.x * 4 + (threadIdx.x >> 6);
    const int lane = threadIdx.x & 63;
    if (n >= NN) return;
    const int beg = offsets[n], end = offsets[n + 1];
    float acc = 0.f;
    int k = beg;
    for (; k + 4 <= end; k += 4) {
        const int s0 = eidx[k], s1 = eidx[k + 1], s2 = eidx[k + 2], s3 = eidx[k + 3];
        const float v0 = bf2f(h16[(size_t)s0 * F + lane]);
        const float v1 = bf2f(h16[(size_t)s1 * F + lane]);
        const float v2 = bf2f(h16[(size_t)s2 * F + lane]);
        const float v3 = bf2f(h16[(size_t)s3 * F + lane]);
        acc += v0; acc += v1; acc += v2; acc += v3;
    }
    for (; k < end; ++k) acc += bf2f(h16[(size_t)eidx[k] * F + lane]);
    const float deg = (float)(end - beg);
    __builtin_nontemporal_store(acc / fmaxf(deg, 1.0f), h_out + (size_t)n * F + lane);
}

extern "C" void kernel_launch(void* const* d_in, const int* in_sizes, int n_in,
                              void* d_out, int out_size, void* d_ws, size_t ws_size,
                              hipStream_t stream)
{
    const float* nfeats = (const float*)d_in[0];
    const float* efeats = (const float*)d_in[1];
    const int*   src    = (const int*)  d_in[2];
    const int*   dst    = (const int*)  d_in[3];
    const float* W_node = (const float*)d_in[4];
    const float* b_node = (const float*)d_in[5];
    const float* W_ni   = (const float*)d_in[6];
    const float* W_nj   = (const float*)d_in[7];
    const float* W_fij  = (const float*)d_in[8];
    const float* bias   = (const float*)d_in[9];

    float* h_out = (float*)d_out;                   // [NN, F]
    float* f_out = (float*)d_out + (size_t)NN * F;  // [NE, F]

    unsigned short* f_ni16 = (unsigned short*)d_ws;            // bf16 tables
    unsigned short* f_nj16 = f_ni16 + (size_t)NN * F;
    unsigned short* h16    = f_nj16 + (size_t)NN * F;
    int*   offsets = (int*)(h16 + (size_t)NN * F);  // NN+1
    int*   cursor  = offsets + (NN + 1);            // NN
    int*   counts  = cursor + NN;                   // NN
    int*   eidx    = counts + NN;                   // NE
    const size_t need = ((size_t)3 * NN * F) * sizeof(unsigned short)
                      + ((size_t)(3 * NN + 1) + NE) * sizeof(int);
    if (ws_size < need) return;

    hipMemsetAsync(counts, 0, (size_t)NN * sizeof(int), stream);

    node_kernel<<<(NN + 255) / 256, 256, 0, stream>>>(nfeats, W_node, b_node, W_ni, W_nj, f_ni16, f_nj16, h16);
    edge_kernel<<<NE / 256, 256, 0, stream>>>(efeats, src, dst, f_ni16, f_nj16, W_fij, bias, f_out);
    hist_kernel<<<(NE + 255) / 256, 256, 0, stream>>>(dst, counts);
    scan_kernel<<<1, 1024, 0, stream>>>(counts, offsets, cursor);
    place_kernel<<<(NE + 255) / 256, 256, 0, stream>>>(src, dst, cursor, eidx);
    gather_kernel<<<(NN + 3) / 4, 256, 0, stream>>>(h16, offsets, eidx, h_out);
}

// Round 8
// 728.103 us; speedup vs baseline: 1.9201x; 1.1987x over previous
//
#include <hip/hip_runtime.h>

#define NN 100000
#define NE 1600000
#define F 64

typedef float f32x4 __attribute__((ext_vector_type(4)));
typedef short bf16x8 __attribute__((ext_vector_type(8)));

__device__ inline unsigned short f2bf(float f) {          // RTNE float->bf16
    unsigned u = __builtin_bit_cast(unsigned, f);
    u = (u + 0x7fffu + ((u >> 16) & 1u)) >> 16;
    return (unsigned short)u;
}
__device__ inline float bf2f(unsigned short b) { return __builtin_bit_cast(float, (unsigned)b << 16); }
__device__ inline float bflo(unsigned u) { return __builtin_bit_cast(float, u << 16); }
__device__ inline float bfhi(unsigned u) { return __builtin_bit_cast(float, u & 0xffff0000u); }

__device__ inline bf16x8 pack8(const f32x4 v0, const f32x4 v1) {
    bf16x8 pk;
    pk[0] = (short)f2bf(v0[0]); pk[1] = (short)f2bf(v0[1]);
    pk[2] = (short)f2bf(v0[2]); pk[3] = (short)f2bf(v0[3]);
    pk[4] = (short)f2bf(v1[0]); pk[5] = (short)f2bf(v1[1]);
    pk[6] = (short)f2bf(v1[2]); pk[7] = (short)f2bf(v1[3]);
    return pk;
}

// ---------------- node transform via bf16 MFMA ----------------
// A = nfeats tile (256x64 bf16, swizzled LDS chunks), B = {W_ni, W_nj, W_node}
// (bf16 LDS [col][k]). A-frags loaded once; per output: 32 MFMAs -> f32 D-tile
// (overlaying A) -> linear 16B bf16 stores. b_node added for the h output.
__global__ __launch_bounds__(256, 2) void node_kernel(
    const float* __restrict__ nfeats,
    const float* __restrict__ W_node, const float* __restrict__ b_node,
    const float* __restrict__ W_ni,   const float* __restrict__ W_nj,
    unsigned short* __restrict__ f_ni16, unsigned short* __restrict__ f_nj16,
    unsigned short* __restrict__ h16)
{
    __shared__ bf16x8 As8[256 * 8];     // 32 KB: A tile, later f32 D half-tiles [256][32]
    __shared__ bf16x8 Ws8[3 * 64 * 8];  // 24 KB: 3 weight tiles
    float* Df = reinterpret_cast<float*>(As8);

    const int t = threadIdx.x;
    const int w = t >> 6, lane = t & 63;
    const int tile0 = blockIdx.x * 256;

    // ---- stage 3 W matrices: [col][k] bf16, slot-swizzled
    {
        const float* Wp0 = W_ni; const float* Wp1 = W_nj; const float* Wp2 = W_node;
#pragma unroll
        for (int m = 0; m < 3; ++m) {
            const float* Wp = (m == 0) ? Wp0 : (m == 1) ? Wp1 : Wp2;
            const f32x4* gw = reinterpret_cast<const f32x4*>(Wp);
#pragma unroll
            for (int i = 0; i < 2; ++i) {
                const int c = i * 256 + t;          // chunk 0..511
                const int row = c >> 3, slot = c & 7;
                Ws8[m * 512 + row * 8 + (slot ^ (row & 7))] = pack8(gw[2 * c], gw[2 * c + 1]);
            }
        }
    }
    // ---- stage A: nfeats tile (row-guarded tail), bf16 swizzled chunks
    {
        const f32x4* gsrc = reinterpret_cast<const f32x4*>(nfeats + (size_t)tile0 * F);
#pragma unroll
        for (int i = 0; i < 8; ++i) {
            const int c = i * 256 + t;              // chunk 0..2047
            const int row = c >> 3, slot = c & 7;
            f32x4 v0 = f32x4{0.f, 0.f, 0.f, 0.f}, v1 = f32x4{0.f, 0.f, 0.f, 0.f};
            if (tile0 + row < NN) { v0 = gsrc[2 * c]; v1 = gsrc[2 * c + 1]; }
            As8[row * 8 + (slot ^ (row & 7))] = pack8(v0, v1);
        }
    }
    __syncthreads();

    // ---- A fragments into VGPRs (live across all 3 outputs)
    bf16x8 af[4][2];
#pragma unroll
    for (int mt = 0; mt < 4; ++mt)
#pragma unroll
        for (int ks = 0; ks < 2; ++ks) {
            const int row = w * 64 + mt * 16 + (lane & 15);
            const int kslot = ks * 4 + (lane >> 4);
            af[mt][ks] = As8[row * 8 + (kslot ^ (row & 7))];
        }
    __syncthreads();        // A LDS dead -> Df usable

#pragma unroll
    for (int m = 0; m < 3; ++m) {
        unsigned short* outp = (m == 0) ? f_ni16 : (m == 1) ? f_nj16 : h16;

        bf16x8 bfr[4][2];
#pragma unroll
        for (int nt = 0; nt < 4; ++nt)
#pragma unroll
            for (int ks = 0; ks < 2; ++ks) {
                const int c = nt * 16 + (lane & 15);
                const int kslot = ks * 4 + (lane >> 4);
                bfr[nt][ks] = Ws8[m * 512 + c * 8 + (kslot ^ (c & 7))];
            }

        f32x4 acc[4][4];
#pragma unroll
        for (int mt = 0; mt < 4; ++mt)
#pragma unroll
            for (int nt = 0; nt < 4; ++nt) acc[mt][nt] = f32x4{0.f, 0.f, 0.f, 0.f};
#pragma unroll
        for (int ks = 0; ks < 2; ++ks)
#pragma unroll
            for (int mt = 0; mt < 4; ++mt)
#pragma unroll
                for (int nt = 0; nt < 4; ++nt)
                    acc[mt][nt] = __builtin_amdgcn_mfma_f32_16x16x32_bf16(
                        af[mt][ks], bfr[nt][ks], acc[mt][nt], 0, 0, 0);

#pragma unroll
        for (int half = 0; half < 2; ++half) {
            // scatter acc -> rotate-swizzled f32 D-tile (+ b_node for h)
#pragma unroll
            for (int mt = 0; mt < 4; ++mt)
#pragma unroll
                for (int ntl = 0; ntl < 2; ++ntl) {
#pragma unroll
                    for (int r = 0; r < 4; ++r) {
                        const int row = w * 64 + mt * 16 + (lane >> 4) * 4 + r;
                        const int col = ntl * 16 + (lane & 15);   // 0..31 local
                        float v = acc[mt][half * 2 + ntl][r];
                        if (m == 2) v += b_node[half * 32 + col];
                        Df[row * 32 + ((col + row) & 31)] = v;
                    }
                }
            __syncthreads();

            // linear stores: 16B (8 bf16) per chunk, full-line coverage, row-guarded
#pragma unroll
            for (int i = 0; i < 4; ++i) {
                const int idx = i * 256 + t;        // 0..1023
                const int row = idx >> 2;           // 0..255
                const int c8 = (idx & 3) << 3;      // 0,8,16,24
                if (tile0 + row < NN) {
                    const float* b = Df + row * 32;
                    uint4 pk;
                    unsigned u[4];
#pragma unroll
                    for (int p = 0; p < 4; ++p) {
                        const unsigned lo = f2bf(b[(c8 + 2 * p + 0 + row) & 31]);
                        const unsigned hi = f2bf(b[(c8 + 2 * p + 1 + row) & 31]);
                        u[p] = lo | (hi << 16);
                    }
                    pk.x = u[0]; pk.y = u[1]; pk.z = u[2]; pk.w = u[3];
                    *reinterpret_cast<uint4*>(outp + (size_t)(tile0 + row) * F + half * 32 + c8) = pk;
                }
            }
            __syncthreads();
        }
    }
}

// ---------------- edge update via bf16 MFMA (unchanged from round 7) ----------------
__global__ __launch_bounds__(256) void edge_kernel(
    const float* __restrict__ efeats,
    const int* __restrict__ src, const int* __restrict__ dst,
    const unsigned short* __restrict__ f_ni16, const unsigned short* __restrict__ f_nj16,
    const float* __restrict__ W_fij, const float* __restrict__ bias,
    float* __restrict__ f_out)
{
    __shared__ bf16x8 As8[256 * 8];   // 32 KB: A tile / later D half-tile (f32 [256][32])
    __shared__ bf16x8 Ws8[64 * 8];    //  8 KB: W tile
    float* Df = reinterpret_cast<float*>(As8);

    const int t = threadIdx.x;
    const int w = t >> 6, lane = t & 63;
    const int tile0 = blockIdx.x * 256;
    const int e = tile0 + t;
    const int s = src[e], d = dst[e];

    {
        const f32x4* gw = reinterpret_cast<const f32x4*>(W_fij);
#pragma unroll
        for (int i = 0; i < 2; ++i) {
            const int c = i * 256 + t;
            const int row = c >> 3, slot = c & 7;
            Ws8[row * 8 + (slot ^ (row & 7))] = pack8(gw[2 * c], gw[2 * c + 1]);
        }
    }
    {
        const f32x4* gsrc = reinterpret_cast<const f32x4*>(efeats + (size_t)tile0 * F);
#pragma unroll
        for (int i = 0; i < 8; ++i) {
            const int c = i * 256 + t;
            const int row = c >> 3, slot = c & 7;
            const f32x4 v0 = __builtin_nontemporal_load(gsrc + 2 * c);
            const f32x4 v1 = __builtin_nontemporal_load(gsrc + 2 * c + 1);
            As8[row * 8 + (slot ^ (row & 7))] = pack8(v0, v1);
        }
    }
    const uint4* gi = reinterpret_cast<const uint4*>(f_ni16 + (size_t)s * F);
    const uint4* gj = reinterpret_cast<const uint4*>(f_nj16 + (size_t)d * F);
    uint4 vni[4], vnj[4];
#pragma unroll
    for (int i = 0; i < 4; ++i) { vni[i] = gi[i]; vnj[i] = gj[i]; }

    __syncthreads();

    bf16x8 af[4][2], bfr[4][2];
#pragma unroll
    for (int mt = 0; mt < 4; ++mt)
#pragma unroll
        for (int ks = 0; ks < 2; ++ks) {
            const int row = w * 64 + mt * 16 + (lane & 15);
            const int kslot = ks * 4 + (lane >> 4);
            af[mt][ks] = As8[row * 8 + (kslot ^ (row & 7))];
        }
#pragma unroll
    for (int nt = 0; nt < 4; ++nt)
#pragma unroll
        for (int ks = 0; ks < 2; ++ks) {
            const int c = nt * 16 + (lane & 15);
            const int kslot = ks * 4 + (lane >> 4);
            bfr[nt][ks] = Ws8[c * 8 + (kslot ^ (c & 7))];
        }

    f32x4 acc[4][4];
#pragma unroll
    for (int mt = 0; mt < 4; ++mt)
#pragma unroll
        for (int nt = 0; nt < 4; ++nt) acc[mt][nt] = f32x4{0.f, 0.f, 0.f, 0.f};

#pragma unroll
    for (int ks = 0; ks < 2; ++ks)
#pragma unroll
        for (int mt = 0; mt < 4; ++mt)
#pragma unroll
            for (int nt = 0; nt < 4; ++nt)
                acc[mt][nt] = __builtin_amdgcn_mfma_f32_16x16x32_bf16(
                    af[mt][ks], bfr[nt][ks], acc[mt][nt], 0, 0, 0);

    __syncthreads();

    f32x4* gout = reinterpret_cast<f32x4*>(f_out + (size_t)tile0 * F);

#pragma unroll
    for (int half = 0; half < 2; ++half) {
#pragma unroll
        for (int mt = 0; mt < 4; ++mt)
#pragma unroll
            for (int ntl = 0; ntl < 2; ++ntl) {
                const int nt = half * 2 + ntl;
#pragma unroll
                for (int r = 0; r < 4; ++r) {
                    const int row = w * 64 + mt * 16 + (lane >> 4) * 4 + r;
                    const int col = ntl * 16 + (lane & 15);
                    Df[row * 32 + ((col + row) & 31)] = acc[mt][nt][r];
                }
            }
        uint4 nni[4], nnj[4];
        if (half == 0) {
#pragma unroll
            for (int i = 0; i < 4; ++i) { nni[i] = gi[4 + i]; nnj[i] = gj[4 + i]; }
        }
        __syncthreads();

        float* rb = Df + t * 32;
#pragma unroll
        for (int c = 0; c < 32; ++c) {
            float v = rb[(c + t) & 31];
            const unsigned wi = vni[c >> 3][(c >> 1) & 3];
            const unsigned wj = vnj[c >> 3][(c >> 1) & 3];
            v += (c & 1) ? bfhi(wi) : bflo(wi);
            v += (c & 1) ? bfhi(wj) : bflo(wj);
            v += bias[half * 32 + c];
            v = (v > 0.f) ? v : 0.01f * v;
            rb[(c + t) & 31] = v;
        }
        __syncthreads();

#pragma unroll
        for (int i = 0; i < 8; ++i) {
            const int idx = i * 256 + t;
            const int row = idx >> 3;
            const int c4 = (idx & 7) << 2;
            const float* b = Df + row * 32;
            f32x4 v;
            v[0] = b[(c4 + 0 + row) & 31];
            v[1] = b[(c4 + 1 + row) & 31];
            v[2] = b[(c4 + 2 + row) & 31];
            v[3] = b[(c4 + 3 + row) & 31];
            __builtin_nontemporal_store(v, gout + row * 16 + half * 8 + (idx & 7));
        }
        if (half == 0) {
            __syncthreads();
#pragma unroll
            for (int i = 0; i < 4; ++i) { vni[i] = nni[i]; vnj[i] = nnj[i]; }
        }
    }
}

// ---------------- CSR build step 1: in-degree histogram ----------------
__global__ __launch_bounds__(256) void hist_kernel(
    const int* __restrict__ dst, int* __restrict__ counts)
{
    const int e = blockIdx.x * 256 + threadIdx.x;
    if (e >= NE) return;
    atomicAdd(&counts[dst[e]], 1);
}

// ---------------- CSR build step 2: exclusive scan (single block, two-pass) ----------------
__global__ __launch_bounds__(1024) void scan_kernel(
    const int* __restrict__ counts, int* __restrict__ offsets, int* __restrict__ cursor)
{
    __shared__ int sdata[1024];
    const int t = threadIdx.x;
    const int CH = (NN + 1023) / 1024;   // 98
    const int base = t * CH;

    int mysum = 0;
    for (int i = 0; i < CH; ++i) {
        const int idx = base + i;
        if (idx < NN) mysum += counts[idx];
    }
    sdata[t] = mysum;
    __syncthreads();
    for (int off = 1; off < 1024; off <<= 1) {
        int v = (t >= off) ? sdata[t - off] : 0;
        __syncthreads();
        sdata[t] += v;
        __syncthreads();
    }
    int running = sdata[t] - mysum;      // exclusive prefix
    for (int i = 0; i < CH; ++i) {
        const int idx = base + i;
        if (idx < NN) {
            offsets[idx] = running;
            cursor[idx]  = running;
            running += counts[idx];
        }
    }
    if (t == 1023) offsets[NN] = running;   // == NE
}

// ---------------- CSR build step 3: placement ----------------
__global__ __launch_bounds__(256) void place_kernel(
    const int* __restrict__ src, const int* __restrict__ dst,
    int* __restrict__ cursor, int* __restrict__ eidx)
{
    const int e = blockIdx.x * 256 + threadIdx.x;
    if (e >= NE) return;
    const int pos = atomicAdd(&cursor[dst[e]], 1);
    eidx[pos] = src[e];
}

// ---------------- aggregation: wave per node, lane = column, bf16 h ----------------
__global__ __launch_bounds__(256) void gather_kernel(
    const unsigned short* __restrict__ h16, const int* __restrict__ offsets,
    const int* __restrict__ eidx, float* __restrict__ h_out)
{
    const int n = blockIdx.x * 4 + (threadIdx.x >> 6);
    const int lane = threadIdx.x & 63;
    if (n >= NN) return;
    const int beg = offsets[n], end = offsets[n + 1];
    float acc = 0.f;
    int k = beg;
    for (; k + 4 <= end; k += 4) {
        const int s0 = eidx[k], s1 = eidx[k + 1], s2 = eidx[k + 2], s3 = eidx[k + 3];
        const float v0 = bf2f(h16[(size_t)s0 * F + lane]);
        const float v1 = bf2f(h16[(size_t)s1 * F + lane]);
        const float v2 = bf2f(h16[(size_t)s2 * F + lane]);
        const float v3 = bf2f(h16[(size_t)s3 * F + lane]);
        acc += v0; acc += v1; acc += v2; acc += v3;
    }
    for (; k < end; ++k) acc += bf2f(h16[(size_t)eidx[k] * F + lane]);
    const float deg = (float)(end - beg);
    __builtin_nontemporal_store(acc / fmaxf(deg, 1.0f), h_out + (size_t)n * F + lane);
}

extern "C" void kernel_launch(void* const* d_in, const int* in_sizes, int n_in,
                              void* d_out, int out_size, void* d_ws, size_t ws_size,
                              hipStream_t stream)
{
    const float* nfeats = (const float*)d_in[0];
    const float* efeats = (const float*)d_in[1];
    const int*   src    = (const int*)  d_in[2];
    const int*   dst    = (const int*)  d_in[3];
    const float* W_node = (const float*)d_in[4];
    const float* b_node = (const float*)d_in[5];
    const float* W_ni   = (const float*)d_in[6];
    const float* W_nj   = (const float*)d_in[7];
    const float* W_fij  = (const float*)d_in[8];
    const float* bias   = (const float*)d_in[9];

    float* h_out = (float*)d_out;                   // [NN, F]
    float* f_out = (float*)d_out + (size_t)NN * F;  // [NE, F]

    unsigned short* f_ni16 = (unsigned short*)d_ws;            // bf16 tables
    unsigned short* f_nj16 = f_ni16 + (size_t)NN * F;
    unsigned short* h16    = f_nj16 + (size_t)NN * F;
    int*   offsets = (int*)(h16 + (size_t)NN * F);  // NN+1
    int*   cursor  = offsets + (NN + 1);            // NN
    int*   counts  = cursor + NN;                   // NN
    int*   eidx    = counts + NN;                   // NE
    const size_t need = ((size_t)3 * NN * F) * sizeof(unsigned short)
                      + ((size_t)(3 * NN + 1) + NE) * sizeof(int);
    if (ws_size < need) return;

    hipMemsetAsync(counts, 0, (size_t)NN * sizeof(int), stream);

    node_kernel<<<(NN + 255) / 256, 256, 0, stream>>>(nfeats, W_node, b_node, W_ni, W_nj, f_ni16, f_nj16, h16);
    edge_kernel<<<NE / 256, 256, 0, stream>>>(efeats, src, dst, f_ni16, f_nj16, W_fij, bias, f_out);
    hist_kernel<<<(NE + 255) / 256, 256, 0, stream>>>(dst, counts);
    scan_kernel<<<1, 1024, 0, stream>>>(counts, offsets, cursor);
    place_kernel<<<(NE + 255) / 256, 256, 0, stream>>>(src, dst, cursor, eidx);
    gather_kernel<<<(NN + 3) / 4, 256, 0, stream>>>(h16, offsets, eidx, h_out);
}

// Round 9
// 484.353 us; speedup vs baseline: 2.8864x; 1.5032x over previous
//
#include <hip/hip_runtime.h>

#define NN 100000
#define NE 1600000
#define F 64
#define NSB ((NN + 255) / 256)   // 391 scan blocks

typedef float f32x4 __attribute__((ext_vector_type(4)));
typedef short bf16x8 __attribute__((ext_vector_type(8)));

__device__ inline unsigned short f2bf(float f) {          // RTNE float->bf16
    unsigned u = __builtin_bit_cast(unsigned, f);
    u = (u + 0x7fffu + ((u >> 16) & 1u)) >> 16;
    return (unsigned short)u;
}
__device__ inline float bf2f(unsigned short b) { return __builtin_bit_cast(float, (unsigned)b << 16); }
__device__ inline float bflo(unsigned u) { return __builtin_bit_cast(float, u << 16); }
__device__ inline float bfhi(unsigned u) { return __builtin_bit_cast(float, u & 0xffff0000u); }

__device__ inline bf16x8 pack8(const f32x4 v0, const f32x4 v1) {
    bf16x8 pk;
    pk[0] = (short)f2bf(v0[0]); pk[1] = (short)f2bf(v0[1]);
    pk[2] = (short)f2bf(v0[2]); pk[3] = (short)f2bf(v0[3]);
    pk[4] = (short)f2bf(v1[0]); pk[5] = (short)f2bf(v1[1]);
    pk[6] = (short)f2bf(v1[2]); pk[7] = (short)f2bf(v1[3]);
    return pk;
}

// ---------------- node transform via bf16 MFMA ----------------
__global__ __launch_bounds__(256, 2) void node_kernel(
    const float* __restrict__ nfeats,
    const float* __restrict__ W_node, const float* __restrict__ b_node,
    const float* __restrict__ W_ni,   const float* __restrict__ W_nj,
    unsigned short* __restrict__ f_ni16, unsigned short* __restrict__ f_nj16,
    unsigned short* __restrict__ h16)
{
    __shared__ bf16x8 As8[256 * 8];     // 32 KB: A tile, later f32 D half-tiles [256][32]
    __shared__ bf16x8 Ws8[3 * 64 * 8];  // 24 KB: 3 weight tiles
    float* Df = reinterpret_cast<float*>(As8);

    const int t = threadIdx.x;
    const int w = t >> 6, lane = t & 63;
    const int tile0 = blockIdx.x * 256;

    {
        const float* Wp0 = W_ni; const float* Wp1 = W_nj; const float* Wp2 = W_node;
#pragma unroll
        for (int m = 0; m < 3; ++m) {
            const float* Wp = (m == 0) ? Wp0 : (m == 1) ? Wp1 : Wp2;
            const f32x4* gw = reinterpret_cast<const f32x4*>(Wp);
#pragma unroll
            for (int i = 0; i < 2; ++i) {
                const int c = i * 256 + t;
                const int row = c >> 3, slot = c & 7;
                Ws8[m * 512 + row * 8 + (slot ^ (row & 7))] = pack8(gw[2 * c], gw[2 * c + 1]);
            }
        }
    }
    {
        const f32x4* gsrc = reinterpret_cast<const f32x4*>(nfeats + (size_t)tile0 * F);
#pragma unroll
        for (int i = 0; i < 8; ++i) {
            const int c = i * 256 + t;
            const int row = c >> 3, slot = c & 7;
            f32x4 v0 = f32x4{0.f, 0.f, 0.f, 0.f}, v1 = f32x4{0.f, 0.f, 0.f, 0.f};
            if (tile0 + row < NN) { v0 = gsrc[2 * c]; v1 = gsrc[2 * c + 1]; }
            As8[row * 8 + (slot ^ (row & 7))] = pack8(v0, v1);
        }
    }
    __syncthreads();

    bf16x8 af[4][2];
#pragma unroll
    for (int mt = 0; mt < 4; ++mt)
#pragma unroll
        for (int ks = 0; ks < 2; ++ks) {
            const int row = w * 64 + mt * 16 + (lane & 15);
            const int kslot = ks * 4 + (lane >> 4);
            af[mt][ks] = As8[row * 8 + (kslot ^ (row & 7))];
        }
    __syncthreads();

#pragma unroll
    for (int m = 0; m < 3; ++m) {
        unsigned short* outp = (m == 0) ? f_ni16 : (m == 1) ? f_nj16 : h16;

        bf16x8 bfr[4][2];
#pragma unroll
        for (int nt = 0; nt < 4; ++nt)
#pragma unroll
            for (int ks = 0; ks < 2; ++ks) {
                const int c = nt * 16 + (lane & 15);
                const int kslot = ks * 4 + (lane >> 4);
                bfr[nt][ks] = Ws8[m * 512 + c * 8 + (kslot ^ (c & 7))];
            }

        f32x4 acc[4][4];
#pragma unroll
        for (int mt = 0; mt < 4; ++mt)
#pragma unroll
            for (int nt = 0; nt < 4; ++nt) acc[mt][nt] = f32x4{0.f, 0.f, 0.f, 0.f};
#pragma unroll
        for (int ks = 0; ks < 2; ++ks)
#pragma unroll
            for (int mt = 0; mt < 4; ++mt)
#pragma unroll
                for (int nt = 0; nt < 4; ++nt)
                    acc[mt][nt] = __builtin_amdgcn_mfma_f32_16x16x32_bf16(
                        af[mt][ks], bfr[nt][ks], acc[mt][nt], 0, 0, 0);

#pragma unroll
        for (int half = 0; half < 2; ++half) {
#pragma unroll
            for (int mt = 0; mt < 4; ++mt)
#pragma unroll
                for (int ntl = 0; ntl < 2; ++ntl) {
#pragma unroll
                    for (int r = 0; r < 4; ++r) {
                        const int row = w * 64 + mt * 16 + (lane >> 4) * 4 + r;
                        const int col = ntl * 16 + (lane & 15);
                        float v = acc[mt][half * 2 + ntl][r];
                        if (m == 2) v += b_node[half * 32 + col];
                        Df[row * 32 + ((col + row) & 31)] = v;
                    }
                }
            __syncthreads();

#pragma unroll
            for (int i = 0; i < 4; ++i) {
                const int idx = i * 256 + t;
                const int row = idx >> 2;
                const int c8 = (idx & 3) << 3;
                if (tile0 + row < NN) {
                    const float* b = Df + row * 32;
                    uint4 pk;
                    unsigned u[4];
#pragma unroll
                    for (int p = 0; p < 4; ++p) {
                        const unsigned lo = f2bf(b[(c8 + 2 * p + 0 + row) & 31]);
                        const unsigned hi = f2bf(b[(c8 + 2 * p + 1 + row) & 31]);
                        u[p] = lo | (hi << 16);
                    }
                    pk.x = u[0]; pk.y = u[1]; pk.z = u[2]; pk.w = u[3];
                    *reinterpret_cast<uint4*>(outp + (size_t)(tile0 + row) * F + half * 32 + c8) = pk;
                }
            }
            __syncthreads();
        }
    }
}

// ---------------- edge update via bf16 MFMA ----------------
__global__ __launch_bounds__(256) void edge_kernel(
    const float* __restrict__ efeats,
    const int* __restrict__ src, const int* __restrict__ dst,
    const unsigned short* __restrict__ f_ni16, const unsigned short* __restrict__ f_nj16,
    const float* __restrict__ W_fij, const float* __restrict__ bias,
    float* __restrict__ f_out)
{
    __shared__ bf16x8 As8[256 * 8];   // 32 KB
    __shared__ bf16x8 Ws8[64 * 8];    //  8 KB
    float* Df = reinterpret_cast<float*>(As8);

    const int t = threadIdx.x;
    const int w = t >> 6, lane = t & 63;
    const int tile0 = blockIdx.x * 256;
    const int e = tile0 + t;
    const int s = src[e], d = dst[e];

    {
        const f32x4* gw = reinterpret_cast<const f32x4*>(W_fij);
#pragma unroll
        for (int i = 0; i < 2; ++i) {
            const int c = i * 256 + t;
            const int row = c >> 3, slot = c & 7;
            Ws8[row * 8 + (slot ^ (row & 7))] = pack8(gw[2 * c], gw[2 * c + 1]);
        }
    }
    {
        const f32x4* gsrc = reinterpret_cast<const f32x4*>(efeats + (size_t)tile0 * F);
#pragma unroll
        for (int i = 0; i < 8; ++i) {
            const int c = i * 256 + t;
            const int row = c >> 3, slot = c & 7;
            const f32x4 v0 = __builtin_nontemporal_load(gsrc + 2 * c);
            const f32x4 v1 = __builtin_nontemporal_load(gsrc + 2 * c + 1);
            As8[row * 8 + (slot ^ (row & 7))] = pack8(v0, v1);
        }
    }
    const uint4* gi = reinterpret_cast<const uint4*>(f_ni16 + (size_t)s * F);
    const uint4* gj = reinterpret_cast<const uint4*>(f_nj16 + (size_t)d * F);
    uint4 vni[4], vnj[4];
#pragma unroll
    for (int i = 0; i < 4; ++i) { vni[i] = gi[i]; vnj[i] = gj[i]; }

    __syncthreads();

    bf16x8 af[4][2], bfr[4][2];
#pragma unroll
    for (int mt = 0; mt < 4; ++mt)
#pragma unroll
        for (int ks = 0; ks < 2; ++ks) {
            const int row = w * 64 + mt * 16 + (lane & 15);
            const int kslot = ks * 4 + (lane >> 4);
            af[mt][ks] = As8[row * 8 + (kslot ^ (row & 7))];
        }
#pragma unroll
    for (int nt = 0; nt < 4; ++nt)
#pragma unroll
        for (int ks = 0; ks < 2; ++ks) {
            const int c = nt * 16 + (lane & 15);
            const int kslot = ks * 4 + (lane >> 4);
            bfr[nt][ks] = Ws8[c * 8 + (kslot ^ (c & 7))];
        }

    f32x4 acc[4][4];
#pragma unroll
    for (int mt = 0; mt < 4; ++mt)
#pragma unroll
        for (int nt = 0; nt < 4; ++nt) acc[mt][nt] = f32x4{0.f, 0.f, 0.f, 0.f};

#pragma unroll
    for (int ks = 0; ks < 2; ++ks)
#pragma unroll
        for (int mt = 0; mt < 4; ++mt)
#pragma unroll
            for (int nt = 0; nt < 4; ++nt)
                acc[mt][nt] = __builtin_amdgcn_mfma_f32_16x16x32_bf16(
                    af[mt][ks], bfr[nt][ks], acc[mt][nt], 0, 0, 0);

    __syncthreads();

    f32x4* gout = reinterpret_cast<f32x4*>(f_out + (size_t)tile0 * F);

#pragma unroll
    for (int half = 0; half < 2; ++half) {
#pragma unroll
        for (int mt = 0; mt < 4; ++mt)
#pragma unroll
            for (int ntl = 0; ntl < 2; ++ntl) {
                const int nt = half * 2 + ntl;
#pragma unroll
                for (int r = 0; r < 4; ++r) {
                    const int row = w * 64 + mt * 16 + (lane >> 4) * 4 + r;
                    const int col = ntl * 16 + (lane & 15);
                    Df[row * 32 + ((col + row) & 31)] = acc[mt][nt][r];
                }
            }
        uint4 nni[4], nnj[4];
        if (half == 0) {
#pragma unroll
            for (int i = 0; i < 4; ++i) { nni[i] = gi[4 + i]; nnj[i] = gj[4 + i]; }
        }
        __syncthreads();

        float* rb = Df + t * 32;
#pragma unroll
        for (int c = 0; c < 32; ++c) {
            float v = rb[(c + t) & 31];
            const unsigned wi = vni[c >> 3][(c >> 1) & 3];
            const unsigned wj = vnj[c >> 3][(c >> 1) & 3];
            v += (c & 1) ? bfhi(wi) : bflo(wi);
            v += (c & 1) ? bfhi(wj) : bflo(wj);
            v += bias[half * 32 + c];
            v = (v > 0.f) ? v : 0.01f * v;
            rb[(c + t) & 31] = v;
        }
        __syncthreads();

#pragma unroll
        for (int i = 0; i < 8; ++i) {
            const int idx = i * 256 + t;
            const int row = idx >> 3;
            const int c4 = (idx & 7) << 2;
            const float* b = Df + row * 32;
            f32x4 v;
            v[0] = b[(c4 + 0 + row) & 31];
            v[1] = b[(c4 + 1 + row) & 31];
            v[2] = b[(c4 + 2 + row) & 31];
            v[3] = b[(c4 + 3 + row) & 31];
            __builtin_nontemporal_store(v, gout + row * 16 + half * 8 + (idx & 7));
        }
        if (half == 0) {
            __syncthreads();
#pragma unroll
            for (int i = 0; i < 4; ++i) { vni[i] = nni[i]; vnj[i] = nnj[i]; }
        }
    }
}

// ---------------- CSR build step 1: in-degree histogram ----------------
__global__ __launch_bounds__(256) void hist_kernel(
    const int* __restrict__ dst, int* __restrict__ counts)
{
    const int e = blockIdx.x * 256 + threadIdx.x;
    if (e >= NE) return;
    atomicAdd(&counts[dst[e]], 1);
}

// ---------------- CSR scan, 3-phase device-wide ----------------
// scan1: per-block (256 elems) exclusive scan -> offsets, block total -> blocksums
__global__ __launch_bounds__(256) void scan1_kernel(
    const int* __restrict__ counts, int* __restrict__ offsets, int* __restrict__ blocksums)
{
    __shared__ int sd[256];
    const int t = threadIdx.x;
    const int i = blockIdx.x * 256 + t;
    const int v = (i < NN) ? counts[i] : 0;
    sd[t] = v;
    __syncthreads();
#pragma unroll
    for (int off = 1; off < 256; off <<= 1) {
        const int x = (t >= off) ? sd[t - off] : 0;
        __syncthreads();
        sd[t] += x;
        __syncthreads();
    }
    if (i < NN) offsets[i] = sd[t] - v;          // block-local exclusive
    if (t == 255) blocksums[blockIdx.x] = sd[255];
}

// scan2: single block scans NSB block totals -> exclusive blockpref
__global__ __launch_bounds__(512) void scan2_kernel(
    const int* __restrict__ blocksums, int* __restrict__ blockpref)
{
    __shared__ int sd[512];
    const int t = threadIdx.x;
    const int v = (t < NSB) ? blocksums[t] : 0;
    sd[t] = v;
    __syncthreads();
#pragma unroll
    for (int off = 1; off < 512; off <<= 1) {
        const int x = (t >= off) ? sd[t - off] : 0;
        __syncthreads();
        sd[t] += x;
        __syncthreads();
    }
    if (t < NSB) blockpref[t] = sd[t] - v;       // exclusive
}

// scan3: add block prefix; write final offsets + cursor; offsets[NN] = NE
__global__ __launch_bounds__(256) void scan3_kernel(
    int* __restrict__ offsets, const int* __restrict__ blockpref, int* __restrict__ cursor)
{
    const int i = blockIdx.x * 256 + threadIdx.x;
    if (i < NN) {
        const int o = offsets[i] + blockpref[blockIdx.x];
        offsets[i] = o;
        cursor[i] = o;
    }
    if (i == 0) offsets[NN] = NE;   // all dst in [0,NN) -> total == NE exactly
}

// ---------------- CSR build step 3: placement ----------------
__global__ __launch_bounds__(256) void place_kernel(
    const int* __restrict__ src, const int* __restrict__ dst,
    int* __restrict__ cursor, int* __restrict__ eidx)
{
    const int e = blockIdx.x * 256 + threadIdx.x;
    if (e >= NE) return;
    const int pos = atomicAdd(&cursor[dst[e]], 1);
    eidx[pos] = src[e];
}

// ---------------- aggregation: wave per node, lane = column, bf16 h ----------------
__global__ __launch_bounds__(256) void gather_kernel(
    const unsigned short* __restrict__ h16, const int* __restrict__ offsets,
    const int* __restrict__ eidx, float* __restrict__ h_out)
{
    const int n = blockIdx.x * 4 + (threadIdx.x >> 6);
    const int lane = threadIdx.x & 63;
    if (n >= NN) return;
    const int beg = offsets[n], end = offsets[n + 1];
    float acc = 0.f;
    int k = beg;
    for (; k + 4 <= end; k += 4) {
        const int s0 = eidx[k], s1 = eidx[k + 1], s2 = eidx[k + 2], s3 = eidx[k + 3];
        const float v0 = bf2f(h16[(size_t)s0 * F + lane]);
        const float v1 = bf2f(h16[(size_t)s1 * F + lane]);
        const float v2 = bf2f(h16[(size_t)s2 * F + lane]);
        const float v3 = bf2f(h16[(size_t)s3 * F + lane]);
        acc += v0; acc += v1; acc += v2; acc += v3;
    }
    for (; k < end; ++k) acc += bf2f(h16[(size_t)eidx[k] * F + lane]);
    const float deg = (float)(end - beg);
    __builtin_nontemporal_store(acc / fmaxf(deg, 1.0f), h_out + (size_t)n * F + lane);
}

extern "C" void kernel_launch(void* const* d_in, const int* in_sizes, int n_in,
                              void* d_out, int out_size, void* d_ws, size_t ws_size,
                              hipStream_t stream)
{
    const float* nfeats = (const float*)d_in[0];
    const float* efeats = (const float*)d_in[1];
    const int*   src    = (const int*)  d_in[2];
    const int*   dst    = (const int*)  d_in[3];
    const float* W_node = (const float*)d_in[4];
    const float* b_node = (const float*)d_in[5];
    const float* W_ni   = (const float*)d_in[6];
    const float* W_nj   = (const float*)d_in[7];
    const float* W_fij  = (const float*)d_in[8];
    const float* bias   = (const float*)d_in[9];

    float* h_out = (float*)d_out;                   // [NN, F]
    float* f_out = (float*)d_out + (size_t)NN * F;  // [NE, F]

    unsigned short* f_ni16 = (unsigned short*)d_ws;            // bf16 tables
    unsigned short* f_nj16 = f_ni16 + (size_t)NN * F;
    unsigned short* h16    = f_nj16 + (size_t)NN * F;
    int*   offsets = (int*)(h16 + (size_t)NN * F);  // NN+1
    int*   cursor  = offsets + (NN + 1);            // NN
    int*   counts  = cursor + NN;                   // NN
    int*   eidx    = counts + NN;                   // NE
    int*   blocksums = eidx + NE;                   // NSB
    int*   blockpref = blocksums + NSB;             // NSB
    const size_t need = ((size_t)3 * NN * F) * sizeof(unsigned short)
                      + ((size_t)(3 * NN + 1) + NE + 2 * NSB) * sizeof(int);
    if (ws_size < need) return;

    hipMemsetAsync(counts, 0, (size_t)NN * sizeof(int), stream);

    node_kernel<<<(NN + 255) / 256, 256, 0, stream>>>(nfeats, W_node, b_node, W_ni, W_nj, f_ni16, f_nj16, h16);
    edge_kernel<<<NE / 256, 256, 0, stream>>>(efeats, src, dst, f_ni16, f_nj16, W_fij, bias, f_out);
    hist_kernel<<<(NE + 255) / 256, 256, 0, stream>>>(dst, counts);
    scan1_kernel<<<NSB, 256, 0, stream>>>(counts, offsets, blocksums);
    scan2_kernel<<<1, 512, 0, stream>>>(blocksums, blockpref);
    scan3_kernel<<<NSB, 256, 0, stream>>>(offsets, blockpref, cursor);
    place_kernel<<<(NE + 255) / 256, 256, 0, stream>>>(src, dst, cursor, eidx);
    gather_kernel<<<(NN + 3) / 4, 256, 0, stream>>>(h16, offsets, eidx, h_out);
}

// Round 10
// 432.697 us; speedup vs baseline: 3.2310x; 1.1194x over previous
//
#include <hip/hip_runtime.h>

#define NN 100000
#define NE 1600000
#define F 64
#define NSB ((NN + 255) / 256)   // 391 scan blocks
#define NTB ((NN + 127) / 128)   // 782 node tiles

typedef float f32x4 __attribute__((ext_vector_type(4)));
typedef short bf16x8 __attribute__((ext_vector_type(8)));

__device__ inline unsigned short f2bf(float f) {          // RTNE float->bf16
    unsigned u = __builtin_bit_cast(unsigned, f);
    u = (u + 0x7fffu + ((u >> 16) & 1u)) >> 16;
    return (unsigned short)u;
}
__device__ inline float bf2f(unsigned short b) { return __builtin_bit_cast(float, (unsigned)b << 16); }
__device__ inline float bflo(unsigned u) { return __builtin_bit_cast(float, u << 16); }
__device__ inline float bfhi(unsigned u) { return __builtin_bit_cast(float, u & 0xffff0000u); }

__device__ inline bf16x8 pack8(const f32x4 v0, const f32x4 v1) {
    bf16x8 pk;
    pk[0] = (short)f2bf(v0[0]); pk[1] = (short)f2bf(v0[1]);
    pk[2] = (short)f2bf(v0[2]); pk[3] = (short)f2bf(v0[3]);
    pk[4] = (short)f2bf(v1[0]); pk[5] = (short)f2bf(v1[1]);
    pk[6] = (short)f2bf(v1[2]); pk[7] = (short)f2bf(v1[3]);
    return pk;
}

// ---------------- node transform via bf16 MFMA ----------------
// grid (NTB, 3): blockIdx.x = 128-row tile, blockIdx.y = which weight matrix
// (0: W_ni -> f_ni16, 1: W_nj -> f_nj16, 2: W_node + b_node -> h16).
// m==0 blocks also zero their counts slice (node runs before edge's fused hist).
__global__ __launch_bounds__(256, 2) void node_kernel(
    const float* __restrict__ nfeats,
    const float* __restrict__ W_node, const float* __restrict__ b_node,
    const float* __restrict__ W_ni,   const float* __restrict__ W_nj,
    unsigned short* __restrict__ f_ni16, unsigned short* __restrict__ f_nj16,
    unsigned short* __restrict__ h16, int* __restrict__ counts)
{
    __shared__ bf16x8 As8[128 * 8];   // 16 KB: A tile, later f32 D half-tile [128][32]
    __shared__ bf16x8 Ws8[64 * 8];    //  8 KB: one weight tile
    float* Df = reinterpret_cast<float*>(As8);

    const int t = threadIdx.x;
    const int w = t >> 6, lane = t & 63;
    const int tile0 = blockIdx.x * 128;
    const int m = blockIdx.y;

    if (m == 0 && t < 128 && tile0 + t < NN) counts[tile0 + t] = 0;

    // ---- stage W (one 64x64 matrix): 512 bf16x8 chunks, 2 per thread
    {
        const float* Wp = (m == 0) ? W_ni : (m == 1) ? W_nj : W_node;
        const f32x4* gw = reinterpret_cast<const f32x4*>(Wp);
#pragma unroll
        for (int i = 0; i < 2; ++i) {
            const int c = i * 256 + t;
            const int row = c >> 3, slot = c & 7;
            Ws8[row * 8 + (slot ^ (row & 7))] = pack8(gw[2 * c], gw[2 * c + 1]);
        }
    }
    // ---- stage A: 128 rows, 1024 chunks, 4 per thread (row-guarded)
    {
        const f32x4* gsrc = reinterpret_cast<const f32x4*>(nfeats + (size_t)tile0 * F);
#pragma unroll
        for (int i = 0; i < 4; ++i) {
            const int c = i * 256 + t;
            const int row = c >> 3, slot = c & 7;
            f32x4 v0 = f32x4{0.f, 0.f, 0.f, 0.f}, v1 = f32x4{0.f, 0.f, 0.f, 0.f};
            if (tile0 + row < NN) { v0 = gsrc[2 * c]; v1 = gsrc[2 * c + 1]; }
            As8[row * 8 + (slot ^ (row & 7))] = pack8(v0, v1);
        }
    }
    __syncthreads();

    // ---- A fragments: each wave owns 32 rows (mt in {0,1})
    bf16x8 af[2][2];
#pragma unroll
    for (int mt = 0; mt < 2; ++mt)
#pragma unroll
        for (int ks = 0; ks < 2; ++ks) {
            const int row = w * 32 + mt * 16 + (lane & 15);
            const int kslot = ks * 4 + (lane >> 4);
            af[mt][ks] = As8[row * 8 + (kslot ^ (row & 7))];
        }

    bf16x8 bfr[4][2];
#pragma unroll
    for (int nt = 0; nt < 4; ++nt)
#pragma unroll
        for (int ks = 0; ks < 2; ++ks) {
            const int c = nt * 16 + (lane & 15);
            const int kslot = ks * 4 + (lane >> 4);
            bfr[nt][ks] = Ws8[c * 8 + (kslot ^ (c & 7))];
        }

    f32x4 acc[2][4];
#pragma unroll
    for (int mt = 0; mt < 2; ++mt)
#pragma unroll
        for (int nt = 0; nt < 4; ++nt) acc[mt][nt] = f32x4{0.f, 0.f, 0.f, 0.f};
#pragma unroll
    for (int ks = 0; ks < 2; ++ks)
#pragma unroll
        for (int mt = 0; mt < 2; ++mt)
#pragma unroll
            for (int nt = 0; nt < 4; ++nt)
                acc[mt][nt] = __builtin_amdgcn_mfma_f32_16x16x32_bf16(
                    af[mt][ks], bfr[nt][ks], acc[mt][nt], 0, 0, 0);

    __syncthreads();        // A LDS dead -> Df usable

    unsigned short* outp = (m == 0) ? f_ni16 : (m == 1) ? f_nj16 : h16;

#pragma unroll
    for (int half = 0; half < 2; ++half) {
        // scatter acc -> rotate-swizzled f32 D-tile [128][32] (+ b_node for h)
#pragma unroll
        for (int mt = 0; mt < 2; ++mt)
#pragma unroll
            for (int ntl = 0; ntl < 2; ++ntl) {
#pragma unroll
                for (int r = 0; r < 4; ++r) {
                    const int row = w * 32 + mt * 16 + (lane >> 4) * 4 + r;
                    const int col = ntl * 16 + (lane & 15);   // 0..31 local
                    float v = acc[mt][half * 2 + ntl][r];
                    if (m == 2) v += b_node[half * 32 + col];
                    Df[row * 32 + ((col + row) & 31)] = v;
                }
            }
        __syncthreads();

        // linear stores: 512 chunks of 8 bf16, 2 per thread, row-guarded
#pragma unroll
        for (int i = 0; i < 2; ++i) {
            const int idx = i * 256 + t;        // 0..511
            const int row = idx >> 2;           // 0..127
            const int c8 = (idx & 3) << 3;      // 0,8,16,24
            if (tile0 + row < NN) {
                const float* b = Df + row * 32;
                uint4 pk;
                unsigned u[4];
#pragma unroll
                for (int p = 0; p < 4; ++p) {
                    const unsigned lo = f2bf(b[(c8 + 2 * p + 0 + row) & 31]);
                    const unsigned hi = f2bf(b[(c8 + 2 * p + 1 + row) & 31]);
                    u[p] = lo | (hi << 16);
                }
                pk.x = u[0]; pk.y = u[1]; pk.z = u[2]; pk.w = u[3];
                *reinterpret_cast<uint4*>(outp + (size_t)(tile0 + row) * F + half * 32 + c8) = pk;
            }
        }
        __syncthreads();
    }
}

// ---------------- edge update via bf16 MFMA (+ fused in-degree histogram) ----------------
__global__ __launch_bounds__(256) void edge_kernel(
    const float* __restrict__ efeats,
    const int* __restrict__ src, const int* __restrict__ dst,
    const unsigned short* __restrict__ f_ni16, const unsigned short* __restrict__ f_nj16,
    const float* __restrict__ W_fij, const float* __restrict__ bias,
    float* __restrict__ f_out, int* __restrict__ counts)
{
    __shared__ bf16x8 As8[256 * 8];   // 32 KB
    __shared__ bf16x8 Ws8[64 * 8];    //  8 KB
    float* Df = reinterpret_cast<float*>(As8);

    const int t = threadIdx.x;
    const int w = t >> 6, lane = t & 63;
    const int tile0 = blockIdx.x * 256;
    const int e = tile0 + t;
    const int s = src[e], d = dst[e];

    atomicAdd(&counts[d], 1);        // fused histogram (counts zeroed by node_kernel)

    {
        const f32x4* gw = reinterpret_cast<const f32x4*>(W_fij);
#pragma unroll
        for (int i = 0; i < 2; ++i) {
            const int c = i * 256 + t;
            const int row = c >> 3, slot = c & 7;
            Ws8[row * 8 + (slot ^ (row & 7))] = pack8(gw[2 * c], gw[2 * c + 1]);
        }
    }
    {
        const f32x4* gsrc = reinterpret_cast<const f32x4*>(efeats + (size_t)tile0 * F);
#pragma unroll
        for (int i = 0; i < 8; ++i) {
            const int c = i * 256 + t;
            const int row = c >> 3, slot = c & 7;
            const f32x4 v0 = __builtin_nontemporal_load(gsrc + 2 * c);
            const f32x4 v1 = __builtin_nontemporal_load(gsrc + 2 * c + 1);
            As8[row * 8 + (slot ^ (row & 7))] = pack8(v0, v1);
        }
    }
    const uint4* gi = reinterpret_cast<const uint4*>(f_ni16 + (size_t)s * F);
    const uint4* gj = reinterpret_cast<const uint4*>(f_nj16 + (size_t)d * F);
    uint4 vni[4], vnj[4];
#pragma unroll
    for (int i = 0; i < 4; ++i) { vni[i] = gi[i]; vnj[i] = gj[i]; }

    __syncthreads();

    bf16x8 af[4][2], bfr[4][2];
#pragma unroll
    for (int mt = 0; mt < 4; ++mt)
#pragma unroll
        for (int ks = 0; ks < 2; ++ks) {
            const int row = w * 64 + mt * 16 + (lane & 15);
            const int kslot = ks * 4 + (lane >> 4);
            af[mt][ks] = As8[row * 8 + (kslot ^ (row & 7))];
        }
#pragma unroll
    for (int nt = 0; nt < 4; ++nt)
#pragma unroll
        for (int ks = 0; ks < 2; ++ks) {
            const int c = nt * 16 + (lane & 15);
            const int kslot = ks * 4 + (lane >> 4);
            bfr[nt][ks] = Ws8[c * 8 + (kslot ^ (c & 7))];
        }

    f32x4 acc[4][4];
#pragma unroll
    for (int mt = 0; mt < 4; ++mt)
#pragma unroll
        for (int nt = 0; nt < 4; ++nt) acc[mt][nt] = f32x4{0.f, 0.f, 0.f, 0.f};

#pragma unroll
    for (int ks = 0; ks < 2; ++ks)
#pragma unroll
        for (int mt = 0; mt < 4; ++mt)
#pragma unroll
            for (int nt = 0; nt < 4; ++nt)
                acc[mt][nt] = __builtin_amdgcn_mfma_f32_16x16x32_bf16(
                    af[mt][ks], bfr[nt][ks], acc[mt][nt], 0, 0, 0);

    __syncthreads();

    f32x4* gout = reinterpret_cast<f32x4*>(f_out + (size_t)tile0 * F);

#pragma unroll
    for (int half = 0; half < 2; ++half) {
#pragma unroll
        for (int mt = 0; mt < 4; ++mt)
#pragma unroll
            for (int ntl = 0; ntl < 2; ++ntl) {
                const int nt = half * 2 + ntl;
#pragma unroll
                for (int r = 0; r < 4; ++r) {
                    const int row = w * 64 + mt * 16 + (lane >> 4) * 4 + r;
                    const int col = ntl * 16 + (lane & 15);
                    Df[row * 32 + ((col + row) & 31)] = acc[mt][nt][r];
                }
            }
        uint4 nni[4], nnj[4];
        if (half == 0) {
#pragma unroll
            for (int i = 0; i < 4; ++i) { nni[i] = gi[4 + i]; nnj[i] = gj[4 + i]; }
        }
        __syncthreads();

        float* rb = Df + t * 32;
#pragma unroll
        for (int c = 0; c < 32; ++c) {
            float v = rb[(c + t) & 31];
            const unsigned wi = vni[c >> 3][(c >> 1) & 3];
            const unsigned wj = vnj[c >> 3][(c >> 1) & 3];
            v += (c & 1) ? bfhi(wi) : bflo(wi);
            v += (c & 1) ? bfhi(wj) : bflo(wj);
            v += bias[half * 32 + c];
            v = (v > 0.f) ? v : 0.01f * v;
            rb[(c + t) & 31] = v;
        }
        __syncthreads();

#pragma unroll
        for (int i = 0; i < 8; ++i) {
            const int idx = i * 256 + t;
            const int row = idx >> 3;
            const int c4 = (idx & 7) << 2;
            const float* b = Df + row * 32;
            f32x4 v;
            v[0] = b[(c4 + 0 + row) & 31];
            v[1] = b[(c4 + 1 + row) & 31];
            v[2] = b[(c4 + 2 + row) & 31];
            v[3] = b[(c4 + 3 + row) & 31];
            __builtin_nontemporal_store(v, gout + row * 16 + half * 8 + (idx & 7));
        }
        if (half == 0) {
            __syncthreads();
#pragma unroll
            for (int i = 0; i < 4; ++i) { vni[i] = nni[i]; vnj[i] = nnj[i]; }
        }
    }
}

// ---------------- CSR scan, 3-phase device-wide ----------------
__global__ __launch_bounds__(256) void scan1_kernel(
    const int* __restrict__ counts, int* __restrict__ offsets, int* __restrict__ blocksums)
{
    __shared__ int sd[256];
    const int t = threadIdx.x;
    const int i = blockIdx.x * 256 + t;
    const int v = (i < NN) ? counts[i] : 0;
    sd[t] = v;
    __syncthreads();
#pragma unroll
    for (int off = 1; off < 256; off <<= 1) {
        const int x = (t >= off) ? sd[t - off] : 0;
        __syncthreads();
        sd[t] += x;
        __syncthreads();
    }
    if (i < NN) offsets[i] = sd[t] - v;
    if (t == 255) blocksums[blockIdx.x] = sd[255];
}

__global__ __launch_bounds__(512) void scan2_kernel(
    const int* __restrict__ blocksums, int* __restrict__ blockpref)
{
    __shared__ int sd[512];
    const int t = threadIdx.x;
    const int v = (t < NSB) ? blocksums[t] : 0;
    sd[t] = v;
    __syncthreads();
#pragma unroll
    for (int off = 1; off < 512; off <<= 1) {
        const int x = (t >= off) ? sd[t - off] : 0;
        __syncthreads();
        sd[t] += x;
        __syncthreads();
    }
    if (t < NSB) blockpref[t] = sd[t] - v;
}

__global__ __launch_bounds__(256) void scan3_kernel(
    int* __restrict__ offsets, const int* __restrict__ blockpref, int* __restrict__ cursor)
{
    const int i = blockIdx.x * 256 + threadIdx.x;
    if (i < NN) {
        const int o = offsets[i] + blockpref[blockIdx.x];
        offsets[i] = o;
        cursor[i] = o;
    }
    if (i == 0) offsets[NN] = NE;
}

// ---------------- CSR placement ----------------
__global__ __launch_bounds__(256) void place_kernel(
    const int* __restrict__ src, const int* __restrict__ dst,
    int* __restrict__ cursor, int* __restrict__ eidx)
{
    const int e = blockIdx.x * 256 + threadIdx.x;
    if (e >= NE) return;
    const int pos = atomicAdd(&cursor[dst[e]], 1);
    eidx[pos] = src[e];
}

// ---------------- aggregation: wave per node, lane = column, bf16 h ----------------
__global__ __launch_bounds__(256) void gather_kernel(
    const unsigned short* __restrict__ h16, const int* __restrict__ offsets,
    const int* __restrict__ eidx, float* __restrict__ h_out)
{
    const int n = blockIdx.x * 4 + (threadIdx.x >> 6);
    const int lane = threadIdx.x & 63;
    if (n >= NN) return;
    const int beg = offsets[n], end = offsets[n + 1];
    float acc = 0.f;
    int k = beg;
    for (; k + 4 <= end; k += 4) {
        const int s0 = eidx[k], s1 = eidx[k + 1], s2 = eidx[k + 2], s3 = eidx[k + 3];
        const float v0 = bf2f(h16[(size_t)s0 * F + lane]);
        const float v1 = bf2f(h16[(size_t)s1 * F + lane]);
        const float v2 = bf2f(h16[(size_t)s2 * F + lane]);
        const float v3 = bf2f(h16[(size_t)s3 * F + lane]);
        acc += v0; acc += v1; acc += v2; acc += v3;
    }
    for (; k < end; ++k) acc += bf2f(h16[(size_t)eidx[k] * F + lane]);
    const float deg = (float)(end - beg);
    __builtin_nontemporal_store(acc / fmaxf(deg, 1.0f), h_out + (size_t)n * F + lane);
}

extern "C" void kernel_launch(void* const* d_in, const int* in_sizes, int n_in,
                              void* d_out, int out_size, void* d_ws, size_t ws_size,
                              hipStream_t stream)
{
    const float* nfeats = (const float*)d_in[0];
    const float* efeats = (const float*)d_in[1];
    const int*   src    = (const int*)  d_in[2];
    const int*   dst    = (const int*)  d_in[3];
    const float* W_node = (const float*)d_in[4];
    const float* b_node = (const float*)d_in[5];
    const float* W_ni   = (const float*)d_in[6];
    const float* W_nj   = (const float*)d_in[7];
    const float* W_fij  = (const float*)d_in[8];
    const float* bias   = (const float*)d_in[9];

    float* h_out = (float*)d_out;                   // [NN, F]
    float* f_out = (float*)d_out + (size_t)NN * F;  // [NE, F]

    unsigned short* f_ni16 = (unsigned short*)d_ws;            // bf16 tables
    unsigned short* f_nj16 = f_ni16 + (size_t)NN * F;
    unsigned short* h16    = f_nj16 + (size_t)NN * F;
    int*   offsets = (int*)(h16 + (size_t)NN * F);  // NN+1
    int*   cursor  = offsets + (NN + 1);            // NN
    int*   counts  = cursor + NN;                   // NN
    int*   eidx    = counts + NN;                   // NE
    int*   blocksums = eidx + NE;                   // NSB
    int*   blockpref = blocksums + NSB;             // NSB
    const size_t need = ((size_t)3 * NN * F) * sizeof(unsigned short)
                      + ((size_t)(3 * NN + 1) + NE + 2 * NSB) * sizeof(int);
    if (ws_size < need) return;

    node_kernel<<<dim3(NTB, 3), 256, 0, stream>>>(nfeats, W_node, b_node, W_ni, W_nj,
                                                  f_ni16, f_nj16, h16, counts);
    edge_kernel<<<NE / 256, 256, 0, stream>>>(efeats, src, dst, f_ni16, f_nj16, W_fij, bias,
                                              f_out, counts);
    scan1_kernel<<<NSB, 256, 0, stream>>>(counts, offsets, blocksums);
    scan2_kernel<<<1, 512, 0, stream>>>(blocksums, blockpref);
    scan3_kernel<<<NSB, 256, 0, stream>>>(offsets, blockpref, cursor);
    place_kernel<<<(NE + 255) / 256, 256, 0, stream>>>(src, dst, cursor, eidx);
    gather_kernel<<<(NN + 3) / 4, 256, 0, stream>>>(h16, offsets, eidx, h_out);
}